// Round 1
// baseline (803.081 us; speedup 1.0000x reference)
//
#include <hip/hip_runtime.h>
#include <hip/hip_bf16.h>

// Problem constants
#define NB 8
#define NS 8
#define NT 256
#define ND 256
#define NH 8
#define NDK 64
#define NHD 512
#define NL 2
#define NF 256
#define NR 512
#define NM 128
#define NTOK 16384   // B*S*T
#define NROW 1024    // B*M

typedef __attribute__((ext_vector_type(8))) short short8;
typedef __attribute__((ext_vector_type(4))) float f32x4;

__device__ __forceinline__ unsigned short f2bf(float x) {
    unsigned u = __builtin_bit_cast(unsigned, x);
    unsigned r = (u + 0x7fffu + ((u >> 16) & 1u)) >> 16;
    return (unsigned short)r;
}
__device__ __forceinline__ float bf2f(unsigned short x) {
    return __builtin_bit_cast(float, ((unsigned)x) << 16);
}
__device__ __forceinline__ float wred(float v) {
#pragma unroll
    for (int o = 32; o > 0; o >>= 1) v += __shfl_xor(v, o, 64);
    return v;
}

// ---------------------------------------------------------------------------
// Prep: encoded fp32 -> bf16 X  (token-major [16384][256])
// ---------------------------------------------------------------------------
__global__ __launch_bounds__(256) void prep_x(const float* __restrict__ enc,
                                              unsigned short* __restrict__ XB) {
    size_t idx = ((size_t)blockIdx.x * 256 + threadIdx.x) * 4;
    float4 v = *(const float4*)(enc + idx);
    uint2 pk;
    pk.x = (unsigned)f2bf(v.x) | ((unsigned)f2bf(v.y) << 16);
    pk.y = (unsigned)f2bf(v.z) | ((unsigned)f2bf(v.w) << 16);
    *(uint2*)(XB + idx) = pk;
}

// ---------------------------------------------------------------------------
// Prep: weights -> bf16 transposed chunk-major images.
// Per combo (kv,l,h): W1 chunks [kc][f<256][32] (65536 elems), W2 (+65536),
// W3 [kc][f<64][32] (+131072, 16384 elems).  W1 row 256 (true_u) -> W1L fp32.
// ---------------------------------------------------------------------------
__global__ __launch_bounds__(256) void prep_w(
    const float* __restrict__ kW1, const float* __restrict__ kW2, const float* __restrict__ kW3,
    const float* __restrict__ vW1, const float* __restrict__ vW2, const float* __restrict__ vW3,
    unsigned short* __restrict__ WP, float* __restrict__ W1L) {
    int bid = blockIdx.x;            // 96 blocks
    int kv = bid / 48; int r = bid % 48;
    int stage = r / 16; int lh = r % 16; int l = lh >> 3; int h = lh & 7;
    int combo = ((kv * 2 + l) << 3) | h;
    unsigned short* dst = WP + (size_t)combo * 147456;
    int tid = threadIdx.x;
    if (stage == 0) {
        const float* src = (kv ? vW1 : kW1) + (size_t)(l * 8 + h) * 257 * 256;
        for (int e = tid; e < 65536; e += 256) {
            int f = e & 255, c = e >> 8;
            dst[((c >> 5) * 256 + f) * 32 + (c & 31)] = f2bf(src[(size_t)c * 256 + f]);
        }
        if (tid < 256) W1L[combo * 256 + tid] = src[256 * 256 + tid];
    } else if (stage == 1) {
        const float* src = (kv ? vW2 : kW2) + (size_t)(l * 8 + h) * 256 * 256;
        unsigned short* d2 = dst + 65536;
        for (int e = tid; e < 65536; e += 256) {
            int f = e & 255, c = e >> 8;
            d2[((c >> 5) * 256 + f) * 32 + (c & 31)] = f2bf(src[(size_t)c * 256 + f]);
        }
    } else {
        const float* src = (kv ? vW3 : kW3) + (size_t)(l * 8 + h) * 256 * 64;
        unsigned short* d3 = dst + 131072;
        for (int e = tid; e < 16384; e += 256) {
            int f = e & 63, c = e >> 6;
            d3[((c >> 5) * 64 + f) * 32 + (c & 31)] = f2bf(src[(size_t)c * 64 + f]);
        }
    }
}

// ---------------------------------------------------------------------------
// Fused per-head MLP: X(64tok x 256) -> relu -> 256 -> relu -> 64, bf16 MFMA.
// Transposed formulation H^T = W^T * X^T.  A-frag: A[m=lane&15][k=quad*8+j],
// B-frag: B[k=quad*8+j][n=lane&15], D: row=quad*4+reg, col=lane&15.
// Block: 256 thr (4 waves); grid = tile*32 + combo (combo%8 pins head to XCD).
// Output: KV[(l*2+kv)*NTOK + token][512] bf16 (h*64+dk contiguous).
// ---------------------------------------------------------------------------
__global__ __launch_bounds__(256, 2) void heads_mlp(
    const float* __restrict__ tu, const unsigned short* __restrict__ XB,
    const unsigned short* __restrict__ WP, const float* __restrict__ W1L,
    const float* __restrict__ kb1, const float* __restrict__ kb2, const float* __restrict__ kb3,
    const float* __restrict__ vb1, const float* __restrict__ vb2, const float* __restrict__ vb3,
    unsigned short* __restrict__ KV) {
    __shared__ __align__(16) char smem[59392];
    unsigned short* bufH = (unsigned short*)smem;            // [64][264] bf16
    unsigned short* bufW = (unsigned short*)(smem + 33792);  // [256][40] bf16
    unsigned short* bufX = (unsigned short*)(smem + 54272);  // [64][40]  bf16
    float* trans = (float*)(smem + 33792);                   // [64][68] fp32 (overlays bufW)

    const int tid = threadIdx.x;
    const int wv = tid >> 6, lane = tid & 63, id = lane & 15, quad = lane >> 4;
    const int combo = blockIdx.x & 31, tile = blockIdx.x >> 5;
    const int kvv = combo >> 4, l = (combo >> 3) & 1, h = combo & 7;
    const int r0 = tile * 64;
    const unsigned short* Wc = WP + (size_t)combo * 147456;
    const float* b1 = (kvv ? vb1 : kb1) + (l * 8 + h) * 256;
    const float* b2 = (kvv ? vb2 : kb2) + (l * 8 + h) * 256;
    const float* b3 = (kvv ? vb3 : kb3) + (l * 8 + h) * 64;

    f32x4 acc[4][4];
#pragma unroll
    for (int i = 0; i < 4; ++i)
#pragma unroll
        for (int j = 0; j < 4; ++j) acc[i][j] = (f32x4){0.f, 0.f, 0.f, 0.f};

    // ---------------- stage 1: H1 = relu(X*W1 + b1 + u*w1last) ----------------
    for (int kc = 0; kc < 8; ++kc) {
        __syncthreads();
#pragma unroll
        for (int it = 0; it < 4; ++it) {
            int seg = it * 256 + tid, f = seg >> 2, c8 = seg & 3;
            *(uint4*)(bufW + f * 40 + c8 * 8) = *(const uint4*)(Wc + kc * 8192 + f * 32 + c8 * 8);
        }
        {
            int tok = tid >> 2, c8 = tid & 3;
            *(uint4*)(bufX + tok * 40 + c8 * 8) =
                *(const uint4*)(XB + (((size_t)(r0 + tok)) << 8) + kc * 32 + c8 * 8);
        }
        __syncthreads();
        short8 bfr[4], af[4];
#pragma unroll
        for (int nt = 0; nt < 4; ++nt) bfr[nt] = *(const short8*)(bufX + (nt * 16 + id) * 40 + quad * 8);
#pragma unroll
        for (int ft = 0; ft < 4; ++ft) af[ft] = *(const short8*)(bufW + (wv * 64 + ft * 16 + id) * 40 + quad * 8);
#pragma unroll
        for (int ft = 0; ft < 4; ++ft)
#pragma unroll
            for (int nt = 0; nt < 4; ++nt)
                acc[ft][nt] = __builtin_amdgcn_mfma_f32_16x16x32_bf16(af[ft], bfr[nt], acc[ft][nt], 0, 0, 0);
    }
    __syncthreads();
    {
        float ur[4];
#pragma unroll
        for (int nt = 0; nt < 4; ++nt) ur[nt] = tu[r0 + nt * 16 + id];
#pragma unroll
        for (int ft = 0; ft < 4; ++ft) {
            int f = wv * 64 + ft * 16 + quad * 4;
            float4 bb = *(const float4*)(b1 + f);
            float4 wl = *(const float4*)(W1L + combo * 256 + f);
            const float* bbp = (const float*)&bb;
            const float* wlp = (const float*)&wl;
#pragma unroll
            for (int nt = 0; nt < 4; ++nt) {
                unsigned short p[4];
#pragma unroll
                for (int r = 0; r < 4; ++r) {
                    float v = acc[ft][nt][r] + bbp[r] + ur[nt] * wlp[r];
                    p[r] = f2bf(fmaxf(v, 0.f));
                }
                uint2 pk;
                pk.x = (unsigned)p[0] | ((unsigned)p[1] << 16);
                pk.y = (unsigned)p[2] | ((unsigned)p[3] << 16);
                *(uint2*)(bufH + (nt * 16 + id) * 264 + f) = pk;
            }
        }
    }

    // ---------------- stage 2: H2 = relu(H1*W2 + b2) ----------------
#pragma unroll
    for (int i = 0; i < 4; ++i)
#pragma unroll
        for (int j = 0; j < 4; ++j) acc[i][j] = (f32x4){0.f, 0.f, 0.f, 0.f};
    for (int kc = 0; kc < 8; ++kc) {
        __syncthreads();
#pragma unroll
        for (int it = 0; it < 4; ++it) {
            int seg = it * 256 + tid, f = seg >> 2, c8 = seg & 3;
            *(uint4*)(bufW + f * 40 + c8 * 8) =
                *(const uint4*)(Wc + 65536 + kc * 8192 + f * 32 + c8 * 8);
        }
        __syncthreads();
        short8 bfr[4], af[4];
#pragma unroll
        for (int nt = 0; nt < 4; ++nt)
            bfr[nt] = *(const short8*)(bufH + (nt * 16 + id) * 264 + kc * 32 + quad * 8);
#pragma unroll
        for (int ft = 0; ft < 4; ++ft) af[ft] = *(const short8*)(bufW + (wv * 64 + ft * 16 + id) * 40 + quad * 8);
#pragma unroll
        for (int ft = 0; ft < 4; ++ft)
#pragma unroll
            for (int nt = 0; nt < 4; ++nt)
                acc[ft][nt] = __builtin_amdgcn_mfma_f32_16x16x32_bf16(af[ft], bfr[nt], acc[ft][nt], 0, 0, 0);
    }
    __syncthreads();
#pragma unroll
    for (int ft = 0; ft < 4; ++ft) {
        int f = wv * 64 + ft * 16 + quad * 4;
        float4 bb = *(const float4*)(b2 + f);
        const float* bbp = (const float*)&bb;
#pragma unroll
        for (int nt = 0; nt < 4; ++nt) {
            unsigned short p[4];
#pragma unroll
            for (int r = 0; r < 4; ++r)
                p[r] = f2bf(fmaxf(acc[ft][nt][r] + bbp[r], 0.f));
            uint2 pk;
            pk.x = (unsigned)p[0] | ((unsigned)p[1] << 16);
            pk.y = (unsigned)p[2] | ((unsigned)p[3] << 16);
            *(uint2*)(bufH + (nt * 16 + id) * 264 + f) = pk;
        }
    }

    // ---------------- stage 3: OUT = H2*W3 + b3 (dk=64) ----------------
    f32x4 a3[4];
#pragma unroll
    for (int i = 0; i < 4; ++i) a3[i] = (f32x4){0.f, 0.f, 0.f, 0.f};
    for (int kc = 0; kc < 8; ++kc) {
        __syncthreads();
        {
            int f = tid >> 2, c8 = tid & 3;
            *(uint4*)(bufW + f * 40 + c8 * 8) =
                *(const uint4*)(Wc + 131072 + kc * 2048 + f * 32 + c8 * 8);
        }
        __syncthreads();
        short8 bfr = *(const short8*)(bufH + (wv * 16 + id) * 264 + kc * 32 + quad * 8);
        short8 af[4];
#pragma unroll
        for (int ft = 0; ft < 4; ++ft) af[ft] = *(const short8*)(bufW + (ft * 16 + id) * 40 + quad * 8);
#pragma unroll
        for (int ft = 0; ft < 4; ++ft)
            a3[ft] = __builtin_amdgcn_mfma_f32_16x16x32_bf16(af[ft], bfr, a3[ft], 0, 0, 0);
    }
    __syncthreads();
#pragma unroll
    for (int ft = 0; ft < 4; ++ft) {
        int dk = ft * 16 + quad * 4;
        float4 bb = *(const float4*)(b3 + dk);
        const float* bbp = (const float*)&bb;
        float tmp[4];
#pragma unroll
        for (int r = 0; r < 4; ++r) tmp[r] = a3[ft][r] + bbp[r];
        *(float4*)(trans + (wv * 16 + id) * 68 + dk) = *(float4*)tmp;
    }
    __syncthreads();
    {
        int tok = tid >> 2, part = tid & 3, dk0 = part * 16;
        __align__(16) unsigned short o[16];
#pragma unroll
        for (int j = 0; j < 16; ++j) o[j] = f2bf(trans[tok * 68 + dk0 + j]);
        size_t base = ((size_t)((l * 2 + kvv) * NTOK + r0 + tok)) * 512 + h * 64 + dk0;
        *(uint4*)(KV + base) = *(uint4*)o;
        *(uint4*)(KV + base + 8) = *(uint4*)(o + 8);
    }
}

// ---------------------------------------------------------------------------
// pred = encoded[:, i, mid_idx]  (1024 x 256)
// ---------------------------------------------------------------------------
__global__ __launch_bounds__(64) void gather_pred(const float* __restrict__ enc,
                                                  const int* __restrict__ mid,
                                                  const int* __restrict__ ip,
                                                  float* __restrict__ pred) {
    int row = blockIdx.x;  // b*128+m
    int b = row >> 7, m = row & 127;
    int iv = ip[0];
    int t = mid[m];
    const float* src = enc + (((size_t)(b * NS + iv)) * NT + t) * ND;
    float4 v = *(const float4*)(src + threadIdx.x * 4);
    *(float4*)(pred + (size_t)row * ND + threadIdx.x * 4) = v;
}

// ---------------------------------------------------------------------------
// Generic small fp32 GEMM: out = [relu](X[1024xK] @ W[KxN] + bias [+ res])
// grid (N/64, 16), block 256 (16x16 thr, 4x4 per thread)
// ---------------------------------------------------------------------------
__global__ __launch_bounds__(256) void gemm_f32(const float* __restrict__ X,
                                                const float* __restrict__ W,
                                                const float* __restrict__ bias,
                                                const float* __restrict__ res,
                                                float* __restrict__ out,
                                                int K, int N, int relu) {
    __shared__ float As[64][17];
    __shared__ float Bs[16][68];
    int tid = threadIdx.x;
    int tx = tid & 15, ty = tid >> 4;
    int n0 = blockIdx.x * 64, m0 = blockIdx.y * 64;
    float acc[4][4] = {};
    for (int k0 = 0; k0 < K; k0 += 16) {
        __syncthreads();
        {
            int mm = tid >> 2, kk = (tid & 3) * 4;
            float4 v = *(const float4*)(X + (size_t)(m0 + mm) * K + k0 + kk);
            As[mm][kk] = v.x; As[mm][kk + 1] = v.y; As[mm][kk + 2] = v.z; As[mm][kk + 3] = v.w;
        }
        {
            int kr = tid >> 4, c4 = (tid & 15) * 4;
            float4 v = *(const float4*)(W + (size_t)(k0 + kr) * N + n0 + c4);
            Bs[kr][c4] = v.x; Bs[kr][c4 + 1] = v.y; Bs[kr][c4 + 2] = v.z; Bs[kr][c4 + 3] = v.w;
        }
        __syncthreads();
#pragma unroll
        for (int kk = 0; kk < 16; ++kk) {
            float a0 = As[ty * 4 + 0][kk], a1 = As[ty * 4 + 1][kk];
            float a2 = As[ty * 4 + 2][kk], a3 = As[ty * 4 + 3][kk];
            float b0 = Bs[kk][tx * 4 + 0], b1 = Bs[kk][tx * 4 + 1];
            float b2 = Bs[kk][tx * 4 + 2], b3 = Bs[kk][tx * 4 + 3];
            acc[0][0] += a0 * b0; acc[0][1] += a0 * b1; acc[0][2] += a0 * b2; acc[0][3] += a0 * b3;
            acc[1][0] += a1 * b0; acc[1][1] += a1 * b1; acc[1][2] += a1 * b2; acc[1][3] += a1 * b3;
            acc[2][0] += a2 * b0; acc[2][1] += a2 * b1; acc[2][2] += a2 * b2; acc[2][3] += a2 * b3;
            acc[3][0] += a3 * b0; acc[3][1] += a3 * b1; acc[3][2] += a3 * b2; acc[3][3] += a3 * b3;
        }
    }
#pragma unroll
    for (int i = 0; i < 4; ++i) {
        int mm = m0 + ty * 4 + i;
#pragma unroll
        for (int j = 0; j < 4; ++j) {
            int nn = n0 + tx * 4 + j;
            float v = acc[i][j] + bias[nn];
            if (res) v += res[(size_t)mm * N + nn];
            if (relu) v = fmaxf(v, 0.f);
            out[(size_t)mm * N + nn] = v;
        }
    }
}

// ---------------------------------------------------------------------------
// Attention (2 neighbors, softmax over n, sum over s) + residual + LN1.
// One wave per (b,m) row.  grid 256 x 256 thr.
// ---------------------------------------------------------------------------
__global__ __launch_bounds__(256) void attn_ln(
    const float* __restrict__ attv, const unsigned short* __restrict__ keys,
    const unsigned short* __restrict__ vals, const int* __restrict__ left,
    const int* __restrict__ right, const int* __restrict__ ip,
    const float* __restrict__ g, const float* __restrict__ bb,
    float* __restrict__ xout) {
    int tid = threadIdx.x, wv = tid >> 6, lane = tid & 63;
    int gid = blockIdx.x * 4 + wv;  // 0..1023 = b*128+m
    int b = gid >> 7, m = gid & 127;
    int iv = ip[0];
    int lt = left[m], rt = right[m];
    float av[8], att[8];
#pragma unroll
    for (int h = 0; h < 8; ++h) {
        av[h] = attv[(size_t)gid * 512 + h * 64 + lane];
        att[h] = 0.f;
    }
    for (int s = 0; s < 8; ++s) {
        int t1 = (s < iv) ? m : rt;
        size_t o0 = ((size_t)((b * 8 + s) * 256 + lt)) * 512 + lane;
        size_t o1 = ((size_t)((b * 8 + s) * 256 + t1)) * 512 + lane;
#pragma unroll
        for (int h = 0; h < 8; ++h) {
            float k0 = bf2f(keys[o0 + h * 64]);
            float k1 = bf2f(keys[o1 + h * 64]);
            float p0 = wred(av[h] * k0) * 0.125f;
            float p1 = wred(av[h] * k1) * 0.125f;
            float mx = fmaxf(p0, p1);
            float e0 = expf(p0 - mx), e1 = expf(p1 - mx);
            float inv = 1.f / (e0 + e1);
            float w0 = e0 * inv, w1 = e1 * inv;
            float v0 = bf2f(vals[o0 + h * 64]);
            float v1 = bf2f(vals[o1 + h * 64]);
            att[h] += w0 * v0 + w1 * v1;
        }
    }
    float xp[8], sum = 0.f;
#pragma unroll
    for (int h = 0; h < 8; ++h) { xp[h] = av[h] + att[h]; sum += xp[h]; }
    float mu = wred(sum) * (1.f / 512.f);
    float s2 = 0.f;
#pragma unroll
    for (int h = 0; h < 8; ++h) { float d = xp[h] - mu; s2 += d * d; }
    float rs = rsqrtf(wred(s2) * (1.f / 512.f) + 1e-5f);
#pragma unroll
    for (int h = 0; h < 8; ++h)
        xout[(size_t)gid * 512 + h * 64 + lane] =
            (xp[h] - mu) * rs * g[h * 64 + lane] + bb[h * 64 + lane];
}

// ---------------------------------------------------------------------------
// LayerNorm over 512, one wave per row. grid 256 x 256 thr.
// ---------------------------------------------------------------------------
__global__ __launch_bounds__(256) void ln_k(const float* __restrict__ in,
                                            const float* __restrict__ g,
                                            const float* __restrict__ bb,
                                            float* __restrict__ out) {
    int tid = threadIdx.x, wv = tid >> 6, lane = tid & 63;
    int gid = blockIdx.x * 4 + wv;
    float x[8], sum = 0.f;
#pragma unroll
    for (int h = 0; h < 8; ++h) { x[h] = in[(size_t)gid * 512 + h * 64 + lane]; sum += x[h]; }
    float mu = wred(sum) * (1.f / 512.f);
    float s2 = 0.f;
#pragma unroll
    for (int h = 0; h < 8; ++h) { float d = x[h] - mu; s2 += d * d; }
    float rs = rsqrtf(wred(s2) * (1.f / 512.f) + 1e-5f);
#pragma unroll
    for (int h = 0; h < 8; ++h)
        out[(size_t)gid * 512 + h * 64 + lane] =
            (x[h] - mu) * rs * g[h * 64 + lane] + bb[h * 64 + lane];
}

// ---------------------------------------------------------------------------
extern "C" void kernel_launch(void* const* d_in, const int* in_sizes, int n_in,
                              void* d_out, int out_size, void* d_ws, size_t ws_size,
                              hipStream_t stream) {
    const float* encoded = (const float*)d_in[0];
    const float* true_u  = (const float*)d_in[1];
    const int* mid_idx   = (const int*)d_in[2];
    const int* left_idx  = (const int*)d_in[3];
    const int* right_idx = (const int*)d_in[4];
    const int* ip        = (const int*)d_in[5];
    const float* ds_W = (const float*)d_in[6];
    const float* ds_b = (const float*)d_in[7];
    const float* kW1 = (const float*)d_in[8];
    const float* kb1 = (const float*)d_in[9];
    const float* kW2 = (const float*)d_in[10];
    const float* kb2 = (const float*)d_in[11];
    const float* kW3 = (const float*)d_in[12];
    const float* kb3 = (const float*)d_in[13];
    const float* vW1 = (const float*)d_in[14];
    const float* vb1 = (const float*)d_in[15];
    const float* vW2 = (const float*)d_in[16];
    const float* vb2 = (const float*)d_in[17];
    const float* vW3 = (const float*)d_in[18];
    const float* vb3 = (const float*)d_in[19];
    const float* ln1_g = (const float*)d_in[20];
    const float* ln1_b = (const float*)d_in[21];
    const float* ln2_g = (const float*)d_in[22];
    const float* ln2_b = (const float*)d_in[23];
    const float* ffW1 = (const float*)d_in[24];
    const float* ffb1 = (const float*)d_in[25];
    const float* ffW2 = (const float*)d_in[26];
    const float* ffb2 = (const float*)d_in[27];
    const float* deW1 = (const float*)d_in[28];
    const float* deb1 = (const float*)d_in[29];
    const float* deW2 = (const float*)d_in[30];
    const float* deb2 = (const float*)d_in[31];
    const float* deW3 = (const float*)d_in[32];
    const float* deb3 = (const float*)d_in[33];

    char* ws = (char*)d_ws;
    unsigned short* XB  = (unsigned short*)(ws + 0);          // 8,388,608 B
    unsigned short* WP  = (unsigned short*)(ws + 8388608);    // 9,437,184 B
    float* W1L          = (float*)(ws + 17825792);            // 32,768 B
    unsigned short* KV  = (unsigned short*)(ws + 17858560);   // 67,108,864 B
    float* ATTV         = (float*)(ws + 84967424);            // 2 MB
    float* XBUF         = (float*)(ws + 87064576);
    float* FBUF         = (float*)(ws + 89161728);
    float* YBUF         = (float*)(ws + 91258880);
    float* PRED         = (float*)(ws + 93356032);            // 1 MB, end ~94.4 MB

    prep_x<<<4096, 256, 0, stream>>>(encoded, XB);
    prep_w<<<96, 256, 0, stream>>>(kW1, kW2, kW3, vW1, vW2, vW3, WP, W1L);
    heads_mlp<<<8192, 256, 0, stream>>>(true_u, XB, WP, W1L, kb1, kb2, kb3,
                                        vb1, vb2, vb3, KV);
    gather_pred<<<1024, 64, 0, stream>>>(encoded, mid_idx, ip, PRED);
    gemm_f32<<<dim3(8, 16), 256, 0, stream>>>(PRED, ds_W, ds_b, nullptr, ATTV, 256, 512, 0);
    for (int l = 0; l < 2; ++l) {
        const unsigned short* keys = KV + (size_t)(l * 2) * NTOK * NHD;
        const unsigned short* vals = KV + (size_t)(l * 2 + 1) * NTOK * NHD;
        attn_ln<<<256, 256, 0, stream>>>(ATTV, keys, vals, left_idx, right_idx, ip,
                                         ln1_g + l * 512, ln1_b + l * 512, XBUF);
        gemm_f32<<<dim3(8, 16), 256, 0, stream>>>(XBUF, ffW1 + (size_t)l * 512 * 512,
                                                  ffb1 + l * 512, nullptr, FBUF, 512, 512, 1);
        gemm_f32<<<dim3(8, 16), 256, 0, stream>>>(FBUF, ffW2 + (size_t)l * 512 * 512,
                                                  ffb2 + l * 512, XBUF, YBUF, 512, 512, 0);
        ln_k<<<256, 256, 0, stream>>>(YBUF, ln2_g + l * 512, ln2_b + l * 512, ATTV);
    }
    gemm_f32<<<dim3(4, 16), 256, 0, stream>>>(ATTV, deW1, deb1, nullptr, FBUF, 512, 256, 1);
    gemm_f32<<<dim3(4, 16), 256, 0, stream>>>(FBUF, deW2, deb2, nullptr, YBUF, 256, 256, 1);
    gemm_f32<<<dim3(8, 16), 256, 0, stream>>>(YBUF, deW3, deb3, nullptr, (float*)d_out, 256, 512, 0);
}

// Round 2
// 578.034 us; speedup vs baseline: 1.3893x; 1.3893x over previous
//
#include <hip/hip_runtime.h>
#include <hip/hip_bf16.h>

// Problem constants
#define NB 8
#define NS 8
#define NT 256
#define ND 256
#define NH 8
#define NDK 64
#define NHD 512
#define NL 2
#define NF 256
#define NR 512
#define NM 128
#define NTOK 16384   // B*S*T
#define NROW 1024    // B*M

typedef __attribute__((ext_vector_type(8))) short short8;
typedef __attribute__((ext_vector_type(4))) float f32x4;

__device__ __forceinline__ unsigned short f2bf(float x) {
    unsigned u = __builtin_bit_cast(unsigned, x);
    unsigned r = (u + 0x7fffu + ((u >> 16) & 1u)) >> 16;
    return (unsigned short)r;
}
__device__ __forceinline__ float bf2f(unsigned short x) {
    return __builtin_bit_cast(float, ((unsigned)x) << 16);
}
__device__ __forceinline__ float wred(float v) {
#pragma unroll
    for (int o = 32; o > 0; o >>= 1) v += __shfl_xor(v, o, 64);
    return v;
}

// ---------------------------------------------------------------------------
// Prep: encoded fp32 -> XF bf16 fragment-major:
// XF[tile(128)][kc(8)][g(2)][nt(4)][lane(64)][j(8)]
//   value = X[token = tile*128+g*64+nt*16+(lane&15)][kc*32+(lane>>4)*8+j]
// 524288 frags; one thread per frag. grid 2048 x 256.
// ---------------------------------------------------------------------------
__global__ __launch_bounds__(256) void prep_x(const float* __restrict__ enc,
                                              unsigned short* __restrict__ XF) {
    int gid = blockIdx.x * 256 + threadIdx.x;
    int lane = gid & 63, nt = (gid >> 6) & 3, g = (gid >> 8) & 1;
    int kc = (gid >> 9) & 7, t = gid >> 12;
    int id = lane & 15, quad = lane >> 4;
    int token = t * 128 + g * 64 + nt * 16 + id;
    int c0 = kc * 32 + quad * 8;
    const float* src = enc + (size_t)token * 256 + c0;
    float4 v0 = *(const float4*)(src);
    float4 v1 = *(const float4*)(src + 4);
    uint4 pk;
    pk.x = (unsigned)f2bf(v0.x) | ((unsigned)f2bf(v0.y) << 16);
    pk.y = (unsigned)f2bf(v0.z) | ((unsigned)f2bf(v0.w) << 16);
    pk.z = (unsigned)f2bf(v1.x) | ((unsigned)f2bf(v1.y) << 16);
    pk.w = (unsigned)f2bf(v1.z) | ((unsigned)f2bf(v1.w) << 16);
    *(uint4*)(XF + (size_t)gid * 8) = pk;
}

// ---------------------------------------------------------------------------
// Prep: head weights -> bf16 fragment-major images per combo (kv,l,h):
//  WF1: [kc(8)][ftile(16)][lane(64)][j(8)]  = W1^T frag  (65536 halves)
//  WF2: same (+65536)
//  WF3: [kc(8)][ftile(4)][lane][j]          (+131072, 16384 halves)
//  frag value = W[k = kc*32+quad*8+j][f = ftile*16+id]
//  W1 row 256 (true_u) -> W1L fp32.
// ---------------------------------------------------------------------------
__global__ __launch_bounds__(256) void prep_w(
    const float* __restrict__ kW1, const float* __restrict__ kW2, const float* __restrict__ kW3,
    const float* __restrict__ vW1, const float* __restrict__ vW2, const float* __restrict__ vW3,
    unsigned short* __restrict__ WP, float* __restrict__ W1L) {
    int bid = blockIdx.x;            // 96 blocks
    int kv = bid / 48; int r = bid % 48;
    int stage = r / 16; int lh = r % 16; int l = lh >> 3; int h = lh & 7;
    int combo = ((kv * 2 + l) << 3) | h;
    unsigned short* dst = WP + (size_t)combo * 147456;
    int tid = threadIdx.x;
    if (stage == 0) {
        const float* src = (kv ? vW1 : kW1) + (size_t)(l * 8 + h) * 257 * 256;
        for (int e = tid; e < 65536; e += 256) {
            int j = e & 7, lane = (e >> 3) & 63, ftile = (e >> 9) & 15, kc = e >> 13;
            int id = lane & 15, quad = lane >> 4;
            dst[e] = f2bf(src[(size_t)(kc * 32 + quad * 8 + j) * 256 + ftile * 16 + id]);
        }
        if (tid < 256) W1L[combo * 256 + tid] = src[256 * 256 + tid];
    } else if (stage == 1) {
        const float* src = (kv ? vW2 : kW2) + (size_t)(l * 8 + h) * 256 * 256;
        unsigned short* d2 = dst + 65536;
        for (int e = tid; e < 65536; e += 256) {
            int j = e & 7, lane = (e >> 3) & 63, ftile = (e >> 9) & 15, kc = e >> 13;
            int id = lane & 15, quad = lane >> 4;
            d2[e] = f2bf(src[(size_t)(kc * 32 + quad * 8 + j) * 256 + ftile * 16 + id]);
        }
    } else {
        const float* src = (kv ? vW3 : kW3) + (size_t)(l * 8 + h) * 256 * 64;
        unsigned short* d3 = dst + 131072;
        for (int e = tid; e < 16384; e += 256) {
            int j = e & 7, lane = (e >> 3) & 63, ftile = (e >> 9) & 3, kc = e >> 11;
            int id = lane & 15, quad = lane >> 4;
            d3[e] = f2bf(src[(size_t)(kc * 32 + quad * 8 + j) * 64 + ftile * 16 + id]);
        }
    }
}

// ---------------------------------------------------------------------------
// Prep: generic gemm weights (ds/ff/de) -> bf16 fragment-major WG images:
// per image: [kc(K/32)][ntile(N/16)][lane(64)][j(8)],
//   value = W[kc*32+quad*8+j][ntile*16+id]
// 188416 frags total; grid 736 x 256.
// ---------------------------------------------------------------------------
__global__ __launch_bounds__(256) void prep_wg(
    const float* __restrict__ dsW, const float* __restrict__ ffW1,
    const float* __restrict__ ffW2, const float* __restrict__ deW1,
    const float* __restrict__ deW2, const float* __restrict__ deW3,
    unsigned short* __restrict__ WG) {
    int fid = blockIdx.x * 256 + threadIdx.x;
    const float* src; int N; int local;
    if (fid < 16384)        { src = dsW;                 N = 512; local = fid; }
    else if (fid < 49152)   { src = ffW1;                N = 512; local = fid - 16384; }
    else if (fid < 81920)   { src = ffW1 + 512 * 512;    N = 512; local = fid - 49152; }
    else if (fid < 114688)  { src = ffW2;                N = 512; local = fid - 81920; }
    else if (fid < 147456)  { src = ffW2 + 512 * 512;    N = 512; local = fid - 114688; }
    else if (fid < 163840)  { src = deW1;                N = 256; local = fid - 147456; }
    else if (fid < 172032)  { src = deW2;                N = 256; local = fid - 163840; }
    else                    { src = deW3;                N = 512; local = fid - 172032; }
    int NTl = N >> 4;
    int lane = local & 63;
    int ntile = (local >> 6) % NTl;
    int kc = (local >> 6) / NTl;
    int id = lane & 15, quad = lane >> 4;
    unsigned short* dst = WG + (size_t)fid * 8;
#pragma unroll
    for (int j = 0; j < 8; ++j)
        dst[j] = f2bf(src[(size_t)(kc * 32 + quad * 8 + j) * N + ntile * 16 + id]);
}

// ---------------------------------------------------------------------------
// Fused per-head MLP v2: 128-token tiles, 8 waves (g = token half, w2 = f
// quarter).  All W and X fragments loaded DIRECTLY from global (fragment-
// major layouts) -> zero LDS staging, 3 barriers per block.  Only the H
// transpose round-trips LDS ([128][264] bf16, bank-even).
// grid = tile*32 + combo (combo%8 = h pins a combo's blocks to one XCD).
// ---------------------------------------------------------------------------
__global__ __launch_bounds__(512, 4) void heads_mlp(
    const float* __restrict__ tu, const unsigned short* __restrict__ XF,
    const unsigned short* __restrict__ WP, const float* __restrict__ W1L,
    const float* __restrict__ kb1, const float* __restrict__ kb2, const float* __restrict__ kb3,
    const float* __restrict__ vb1, const float* __restrict__ vb2, const float* __restrict__ vb3,
    unsigned short* __restrict__ KV) {
    extern __shared__ unsigned short bufH[];   // [128][264] bf16 = 67584 B

    const int tid = threadIdx.x;
    const int wv = tid >> 6, lane = tid & 63, id = lane & 15, quad = lane >> 4;
    const int g = wv >> 2, w2 = wv & 3;
    const int combo = blockIdx.x & 31, tile = blockIdx.x >> 5;
    const int kvv = combo >> 4, l = (combo >> 3) & 1, h = combo & 7;
    const int r0 = tile * 128;
    const unsigned short* WF1 = WP + (size_t)combo * 147456;
    const unsigned short* WF2 = WF1 + 65536;
    const unsigned short* WF3 = WF1 + 131072;
    const unsigned short* XFt = XF + (size_t)tile * 32768;
    const float* b1 = (kvv ? vb1 : kb1) + (l * 8 + h) * 256;
    const float* b2 = (kvv ? vb2 : kb2) + (l * 8 + h) * 256;
    const float* b3 = (kvv ? vb3 : kb3) + (l * 8 + h) * 64;

    f32x4 acc[4][4];
#pragma unroll
    for (int i = 0; i < 4; ++i)
#pragma unroll
        for (int j = 0; j < 4; ++j) acc[i][j] = (f32x4){0.f, 0.f, 0.f, 0.f};

    // ---------------- stage 1: H1 = relu(X*W1 + b1 + u*w1last) ----------------
    for (int kc = 0; kc < 8; ++kc) {
        short8 af[4], bf[4];
#pragma unroll
        for (int ft = 0; ft < 4; ++ft)
            af[ft] = *(const short8*)(WF1 + (size_t)((kc * 16 + w2 * 4 + ft) * 64 + lane) * 8);
#pragma unroll
        for (int nt = 0; nt < 4; ++nt)
            bf[nt] = *(const short8*)(XFt + (size_t)((((kc * 2 + g) * 4 + nt) * 64 + lane)) * 8);
#pragma unroll
        for (int ft = 0; ft < 4; ++ft)
#pragma unroll
            for (int nt = 0; nt < 4; ++nt)
                acc[ft][nt] = __builtin_amdgcn_mfma_f32_16x16x32_bf16(af[ft], bf[nt], acc[ft][nt], 0, 0, 0);
    }
    {
        float ur[4];
#pragma unroll
        for (int nt = 0; nt < 4; ++nt) ur[nt] = tu[r0 + g * 64 + nt * 16 + id];
#pragma unroll
        for (int ft = 0; ft < 4; ++ft) {
            int fb = w2 * 64 + ft * 16 + quad * 4;
            float4 bb = *(const float4*)(b1 + fb);
            float4 wl = *(const float4*)(W1L + combo * 256 + fb);
            const float* bbp = (const float*)&bb;
            const float* wlp = (const float*)&wl;
#pragma unroll
            for (int nt = 0; nt < 4; ++nt) {
                unsigned short p[4];
#pragma unroll
                for (int r = 0; r < 4; ++r) {
                    float v = acc[ft][nt][r] + bbp[r] + ur[nt] * wlp[r];
                    p[r] = f2bf(fmaxf(v, 0.f));
                }
                uint2 pk;
                pk.x = (unsigned)p[0] | ((unsigned)p[1] << 16);
                pk.y = (unsigned)p[2] | ((unsigned)p[3] << 16);
                *(uint2*)(bufH + (size_t)(g * 64 + nt * 16 + id) * 264 + fb) = pk;
            }
        }
    }
    __syncthreads();

    // ---------------- stage 2: H2 = relu(H1*W2 + b2) ----------------
#pragma unroll
    for (int i = 0; i < 4; ++i)
#pragma unroll
        for (int j = 0; j < 4; ++j) acc[i][j] = (f32x4){0.f, 0.f, 0.f, 0.f};
    for (int kc = 0; kc < 8; ++kc) {
        short8 af[4], bf[4];
#pragma unroll
        for (int ft = 0; ft < 4; ++ft)
            af[ft] = *(const short8*)(WF2 + (size_t)((kc * 16 + w2 * 4 + ft) * 64 + lane) * 8);
#pragma unroll
        for (int nt = 0; nt < 4; ++nt)
            bf[nt] = *(const short8*)(bufH + (size_t)(g * 64 + nt * 16 + id) * 264 + kc * 32 + quad * 8);
#pragma unroll
        for (int ft = 0; ft < 4; ++ft)
#pragma unroll
            for (int nt = 0; nt < 4; ++nt)
                acc[ft][nt] = __builtin_amdgcn_mfma_f32_16x16x32_bf16(af[ft], bf[nt], acc[ft][nt], 0, 0, 0);
    }
    __syncthreads();   // all H1 reads done before overwrite
#pragma unroll
    for (int ft = 0; ft < 4; ++ft) {
        int fb = w2 * 64 + ft * 16 + quad * 4;
        float4 bb = *(const float4*)(b2 + fb);
        const float* bbp = (const float*)&bb;
#pragma unroll
        for (int nt = 0; nt < 4; ++nt) {
            unsigned short p[4];
#pragma unroll
            for (int r = 0; r < 4; ++r)
                p[r] = f2bf(fmaxf(acc[ft][nt][r] + bbp[r], 0.f));
            uint2 pk;
            pk.x = (unsigned)p[0] | ((unsigned)p[1] << 16);
            pk.y = (unsigned)p[2] | ((unsigned)p[3] << 16);
            *(uint2*)(bufH + (size_t)(g * 64 + nt * 16 + id) * 264 + fb) = pk;
        }
    }
    __syncthreads();

    // ---------------- stage 3: OUT = H2*W3 + b3 (dk=64), wave = 16 tokens ----
    f32x4 a3[4];
#pragma unroll
    for (int i = 0; i < 4; ++i) a3[i] = (f32x4){0.f, 0.f, 0.f, 0.f};
    for (int kc = 0; kc < 8; ++kc) {
        short8 af3[4];
#pragma unroll
        for (int ft = 0; ft < 4; ++ft)
            af3[ft] = *(const short8*)(WF3 + (size_t)((kc * 4 + ft) * 64 + lane) * 8);
        short8 b3f = *(const short8*)(bufH + (size_t)(wv * 16 + id) * 264 + kc * 32 + quad * 8);
#pragma unroll
        for (int ft = 0; ft < 4; ++ft)
            a3[ft] = __builtin_amdgcn_mfma_f32_16x16x32_bf16(af3[ft], b3f, a3[ft], 0, 0, 0);
    }
    {
        int token = r0 + wv * 16 + id;
        size_t rowbase = ((size_t)((l * 2 + kvv) * NTOK + token)) * 512 + h * 64;
#pragma unroll
        for (int ft = 0; ft < 4; ++ft) {
            int dk0 = ft * 16 + quad * 4;
            float4 bb = *(const float4*)(b3 + dk0);
            const float* bbp = (const float*)&bb;
            unsigned short p[4];
#pragma unroll
            for (int r = 0; r < 4; ++r) p[r] = f2bf(a3[ft][r] + bbp[r]);
            uint2 pk;
            pk.x = (unsigned)p[0] | ((unsigned)p[1] << 16);
            pk.y = (unsigned)p[2] | ((unsigned)p[3] << 16);
            *(uint2*)(KV + rowbase + dk0) = pk;
        }
    }
}

// ---------------------------------------------------------------------------
// pred = encoded[:, i, mid_idx]  -> bf16 PREDB (1024 x 256)
// ---------------------------------------------------------------------------
__global__ __launch_bounds__(64) void gather_pred(const float* __restrict__ enc,
                                                  const int* __restrict__ mid,
                                                  const int* __restrict__ ip,
                                                  unsigned short* __restrict__ predb) {
    int row = blockIdx.x;  // b*128+m
    int b = row >> 7, m = row & 127;
    int iv = ip[0];
    int t = mid[m];
    const float* src = enc + (((size_t)(b * NS + iv)) * NT + t) * ND;
    float4 v = *(const float4*)(src + threadIdx.x * 4);
    uint2 pk;
    pk.x = (unsigned)f2bf(v.x) | ((unsigned)f2bf(v.y) << 16);
    pk.y = (unsigned)f2bf(v.z) | ((unsigned)f2bf(v.w) << 16);
    *(uint2*)(predb + (size_t)row * ND + threadIdx.x * 4) = pk;
}

// ---------------------------------------------------------------------------
// bf16 MFMA gemm: out = [relu](A[1024xK]bf16 @ W[KxN]bf16 + bias [+ res_f32])
// A token-major bf16 (frags contiguous); W fragment-major (prep_wg).
// grid (N/64, 32), block 256: wave = 1 ntile x 2 mtiles (32 rows).
// ---------------------------------------------------------------------------
__global__ __launch_bounds__(256) void gemm_bf16(
    const unsigned short* __restrict__ A, const unsigned short* __restrict__ WF,
    const float* __restrict__ bias, const float* __restrict__ res,
    float* __restrict__ outf, unsigned short* __restrict__ outb,
    int K, int N, int relu) {
    int tid = threadIdx.x, wv = tid >> 6, lane = tid & 63;
    int id = lane & 15, quad = lane >> 4;
    int ntile = blockIdx.x * 4 + wv;
    int n0 = ntile * 16, m0 = blockIdx.y * 32;
    int NTl = N >> 4, KC = K >> 5;
    f32x4 acc[2];
    acc[0] = (f32x4){0.f, 0.f, 0.f, 0.f};
    acc[1] = (f32x4){0.f, 0.f, 0.f, 0.f};
#pragma unroll 4
    for (int kc = 0; kc < KC; ++kc) {
        short8 bw = *(const short8*)(WF + (size_t)((kc * NTl + ntile) * 64 + lane) * 8);
        short8 a0 = *(const short8*)(A + (size_t)(m0 + id) * K + kc * 32 + quad * 8);
        short8 a1 = *(const short8*)(A + (size_t)(m0 + 16 + id) * K + kc * 32 + quad * 8);
        acc[0] = __builtin_amdgcn_mfma_f32_16x16x32_bf16(a0, bw, acc[0], 0, 0, 0);
        acc[1] = __builtin_amdgcn_mfma_f32_16x16x32_bf16(a1, bw, acc[1], 0, 0, 0);
    }
    float bv = bias[n0 + id];
#pragma unroll
    for (int mt = 0; mt < 2; ++mt) {
#pragma unroll
        for (int r = 0; r < 4; ++r) {
            int row = m0 + mt * 16 + quad * 4 + r;
            int n = n0 + id;
            float v = acc[mt][r] + bv;
            if (res) v += res[(size_t)row * N + n];
            if (relu) v = fmaxf(v, 0.f);
            if (outf) outf[(size_t)row * N + n] = v;
            if (outb) outb[(size_t)row * N + n] = f2bf(v);
        }
    }
}

// ---------------------------------------------------------------------------
// Attention (2 neighbors, softmax over n, sum over s) + residual + LN1.
// One wave per (b,m) row.  grid 256 x 256 thr.  fp32 out + bf16 out.
// ---------------------------------------------------------------------------
__global__ __launch_bounds__(256) void attn_ln(
    const float* __restrict__ attv, const unsigned short* __restrict__ keys,
    const unsigned short* __restrict__ vals, const int* __restrict__ left,
    const int* __restrict__ right, const int* __restrict__ ip,
    const float* __restrict__ g, const float* __restrict__ bb,
    float* __restrict__ xout, unsigned short* __restrict__ xoutb) {
    int tid = threadIdx.x, wv = tid >> 6, lane = tid & 63;
    int gid = blockIdx.x * 4 + wv;  // 0..1023 = b*128+m
    int b = gid >> 7, m = gid & 127;
    int iv = ip[0];
    int lt = left[m], rt = right[m];
    float av[8], att[8];
#pragma unroll
    for (int h = 0; h < 8; ++h) {
        av[h] = attv[(size_t)gid * 512 + h * 64 + lane];
        att[h] = 0.f;
    }
    for (int s = 0; s < 8; ++s) {
        int t1 = (s < iv) ? m : rt;
        size_t o0 = ((size_t)((b * 8 + s) * 256 + lt)) * 512 + lane;
        size_t o1 = ((size_t)((b * 8 + s) * 256 + t1)) * 512 + lane;
#pragma unroll
        for (int h = 0; h < 8; ++h) {
            float k0 = bf2f(keys[o0 + h * 64]);
            float k1 = bf2f(keys[o1 + h * 64]);
            float p0 = wred(av[h] * k0) * 0.125f;
            float p1 = wred(av[h] * k1) * 0.125f;
            float mx = fmaxf(p0, p1);
            float e0 = expf(p0 - mx), e1 = expf(p1 - mx);
            float inv = 1.f / (e0 + e1);
            float w0 = e0 * inv, w1 = e1 * inv;
            float v0 = bf2f(vals[o0 + h * 64]);
            float v1 = bf2f(vals[o1 + h * 64]);
            att[h] += w0 * v0 + w1 * v1;
        }
    }
    float xp[8], sum = 0.f;
#pragma unroll
    for (int h = 0; h < 8; ++h) { xp[h] = av[h] + att[h]; sum += xp[h]; }
    float mu = wred(sum) * (1.f / 512.f);
    float s2 = 0.f;
#pragma unroll
    for (int h = 0; h < 8; ++h) { float d = xp[h] - mu; s2 += d * d; }
    float rs = rsqrtf(wred(s2) * (1.f / 512.f) + 1e-5f);
#pragma unroll
    for (int h = 0; h < 8; ++h) {
        float v = (xp[h] - mu) * rs * g[h * 64 + lane] + bb[h * 64 + lane];
        xout[(size_t)gid * 512 + h * 64 + lane] = v;
        xoutb[(size_t)gid * 512 + h * 64 + lane] = f2bf(v);
    }
}

// ---------------------------------------------------------------------------
// LayerNorm over 512, one wave per row. fp32 out + bf16 out.
// ---------------------------------------------------------------------------
__global__ __launch_bounds__(256) void ln_k(const float* __restrict__ in,
                                            const float* __restrict__ g,
                                            const float* __restrict__ bb,
                                            float* __restrict__ out,
                                            unsigned short* __restrict__ outb) {
    int tid = threadIdx.x, wv = tid >> 6, lane = tid & 63;
    int gid = blockIdx.x * 4 + wv;
    float x[8], sum = 0.f;
#pragma unroll
    for (int h = 0; h < 8; ++h) { x[h] = in[(size_t)gid * 512 + h * 64 + lane]; sum += x[h]; }
    float mu = wred(sum) * (1.f / 512.f);
    float s2 = 0.f;
#pragma unroll
    for (int h = 0; h < 8; ++h) { float d = x[h] - mu; s2 += d * d; }
    float rs = rsqrtf(wred(s2) * (1.f / 512.f) + 1e-5f);
#pragma unroll
    for (int h = 0; h < 8; ++h) {
        float v = (x[h] - mu) * rs * g[h * 64 + lane] + bb[h * 64 + lane];
        out[(size_t)gid * 512 + h * 64 + lane] = v;
        outb[(size_t)gid * 512 + h * 64 + lane] = f2bf(v);
    }
}

// ---------------------------------------------------------------------------
extern "C" void kernel_launch(void* const* d_in, const int* in_sizes, int n_in,
                              void* d_out, int out_size, void* d_ws, size_t ws_size,
                              hipStream_t stream) {
    const float* encoded = (const float*)d_in[0];
    const float* true_u  = (const float*)d_in[1];
    const int* mid_idx   = (const int*)d_in[2];
    const int* left_idx  = (const int*)d_in[3];
    const int* right_idx = (const int*)d_in[4];
    const int* ip        = (const int*)d_in[5];
    const float* ds_W = (const float*)d_in[6];
    const float* ds_b = (const float*)d_in[7];
    const float* kW1 = (const float*)d_in[8];
    const float* kb1 = (const float*)d_in[9];
    const float* kW2 = (const float*)d_in[10];
    const float* kb2 = (const float*)d_in[11];
    const float* kW3 = (const float*)d_in[12];
    const float* kb3 = (const float*)d_in[13];
    const float* vW1 = (const float*)d_in[14];
    const float* vb1 = (const float*)d_in[15];
    const float* vW2 = (const float*)d_in[16];
    const float* vb2 = (const float*)d_in[17];
    const float* vW3 = (const float*)d_in[18];
    const float* vb3 = (const float*)d_in[19];
    const float* ln1_g = (const float*)d_in[20];
    const float* ln1_b = (const float*)d_in[21];
    const float* ln2_g = (const float*)d_in[22];
    const float* ln2_b = (const float*)d_in[23];
    const float* ffW1 = (const float*)d_in[24];
    const float* ffb1 = (const float*)d_in[25];
    const float* ffW2 = (const float*)d_in[26];
    const float* ffb2 = (const float*)d_in[27];
    const float* deW1 = (const float*)d_in[28];
    const float* deb1 = (const float*)d_in[29];
    const float* deW2 = (const float*)d_in[30];
    const float* deb2 = (const float*)d_in[31];
    const float* deW3 = (const float*)d_in[32];
    const float* deb3 = (const float*)d_in[33];

    char* ws = (char*)d_ws;
    unsigned short* XF   = (unsigned short*)(ws + 0);          //  8,388,608
    unsigned short* WP   = (unsigned short*)(ws + 8388608);    //  9,437,184
    float* W1L           = (float*)(ws + 17825792);            //     32,768
    unsigned short* KV   = (unsigned short*)(ws + 17858560);   // 67,108,864
    unsigned short* WG   = (unsigned short*)(ws + 84967424);   //  3,014,656
    float* ATTV          = (float*)(ws + 87982080);            //  2,097,152
    float* XBUF          = (float*)(ws + 90079232);            //  2,097,152
    float* YBUF          = (float*)(ws + 92176384);            //  2,097,152
    unsigned short* PREDB = (unsigned short*)(ws + 94273536);  //    524,288
    unsigned short* ATTVB = (unsigned short*)(ws + 94797824);  //  1,048,576
    unsigned short* XBUFB = (unsigned short*)(ws + 95846400);  //  1,048,576
    unsigned short* FBUFB = (unsigned short*)(ws + 96894976);  //  1,048,576 (end 97,943,552)
    unsigned short* DE1B = XBUFB;   // reuse (free after layers)
    unsigned short* DE2B = FBUFB;

    // WG image offsets (halves)
    unsigned short* WGds  = WG + 0;
    unsigned short* WGff1_0 = WG + 131072;
    unsigned short* WGff1_1 = WG + 393216;
    unsigned short* WGff2_0 = WG + 655360;
    unsigned short* WGff2_1 = WG + 917504;
    unsigned short* WGde1 = WG + 1179648;
    unsigned short* WGde2 = WG + 1310720;
    unsigned short* WGde3 = WG + 1376256;

    prep_x<<<2048, 256, 0, stream>>>(encoded, XF);
    prep_w<<<96, 256, 0, stream>>>(kW1, kW2, kW3, vW1, vW2, vW3, WP, W1L);
    prep_wg<<<736, 256, 0, stream>>>(ds_W, ffW1, ffW2, deW1, deW2, deW3, WG);
    heads_mlp<<<4096, 512, 67584, stream>>>(true_u, XF, WP, W1L, kb1, kb2, kb3,
                                            vb1, vb2, vb3, KV);
    gather_pred<<<1024, 64, 0, stream>>>(encoded, mid_idx, ip, PREDB);
    gemm_bf16<<<dim3(8, 32), 256, 0, stream>>>(PREDB, WGds, ds_b, nullptr,
                                               ATTV, nullptr, 256, 512, 0);
    for (int l = 0; l < 2; ++l) {
        const unsigned short* keys = KV + (size_t)(l * 2) * NTOK * NHD;
        const unsigned short* vals = KV + (size_t)(l * 2 + 1) * NTOK * NHD;
        attn_ln<<<256, 256, 0, stream>>>(ATTV, keys, vals, left_idx, right_idx, ip,
                                         ln1_g + l * 512, ln1_b + l * 512, XBUF, XBUFB);
        gemm_bf16<<<dim3(8, 32), 256, 0, stream>>>(XBUFB, (l ? WGff1_1 : WGff1_0),
                                                   ffb1 + l * 512, nullptr,
                                                   nullptr, FBUFB, 512, 512, 1);
        gemm_bf16<<<dim3(8, 32), 256, 0, stream>>>(FBUFB, (l ? WGff2_1 : WGff2_0),
                                                   ffb2 + l * 512, XBUF,
                                                   YBUF, nullptr, 512, 512, 0);
        ln_k<<<256, 256, 0, stream>>>(YBUF, ln2_g + l * 512, ln2_b + l * 512, ATTV, ATTVB);
    }
    gemm_bf16<<<dim3(4, 32), 256, 0, stream>>>(ATTVB, WGde1, deb1, nullptr,
                                               nullptr, DE1B, 512, 256, 1);
    gemm_bf16<<<dim3(4, 32), 256, 0, stream>>>(DE1B, WGde2, deb2, nullptr,
                                               nullptr, DE2B, 256, 256, 1);
    gemm_bf16<<<dim3(8, 32), 256, 0, stream>>>(DE2B, WGde3, deb3, nullptr,
                                               (float*)d_out, nullptr, 256, 512, 0);
}

// Round 3
// 514.363 us; speedup vs baseline: 1.5613x; 1.1238x over previous
//
#include <hip/hip_runtime.h>
#include <hip/hip_bf16.h>

// Problem constants
#define NB 8
#define NS 8
#define NT 256
#define ND 256
#define NH 8
#define NDK 64
#define NHD 512
#define NL 2
#define NF 256
#define NR 512
#define NM 128
#define NTOK 16384   // B*S*T
#define NROW 1024    // B*M

typedef __attribute__((ext_vector_type(8))) short short8;
typedef __attribute__((ext_vector_type(4))) float f32x4;

__device__ __forceinline__ unsigned short f2bf(float x) {
    unsigned u = __builtin_bit_cast(unsigned, x);
    unsigned r = (u + 0x7fffu + ((u >> 16) & 1u)) >> 16;
    return (unsigned short)r;
}
__device__ __forceinline__ float bf2f(unsigned short x) {
    return __builtin_bit_cast(float, ((unsigned)x) << 16);
}
__device__ __forceinline__ float wred(float v) {
#pragma unroll
    for (int o = 32; o > 0; o >>= 1) v += __shfl_xor(v, o, 64);
    return v;
}

// ---------------------------------------------------------------------------
// Prep: encoded fp32 -> XF bf16 fragment-major, via LDS transpose (coalesced).
// XF[tile(128)][kc(8)][g(2)][nt(4)][lane(64)][j(8)]
//   value = X[token = tile*128+g*64+nt*16+(lane&15)][kc*32+(lane>>4)*8+j]
// Block: 32 tokens x 256 cols.  grid 512 x 256.
// ---------------------------------------------------------------------------
__global__ __launch_bounds__(256) void prep_x(const float* __restrict__ enc,
                                              unsigned short* __restrict__ XF) {
    __shared__ float T[32][257];
    int tid = threadIdx.x;
    int t0 = blockIdx.x * 32;
    const float* src = enc + (size_t)t0 * 256;
#pragma unroll
    for (int it = 0; it < 8; ++it) {
        int f4 = it * 256 + tid;
        int row = f4 >> 6, c = (f4 & 63) * 4;
        float4 v = *(const float4*)(src + row * 256 + c);
        T[row][c] = v.x; T[row][c + 1] = v.y; T[row][c + 2] = v.z; T[row][c + 3] = v.w;
    }
    __syncthreads();
    int tile = t0 >> 7, g = (t0 >> 6) & 1, nt0 = (t0 >> 4) & 3;
#pragma unroll
    for (int i = 0; i < 32; i += 8) {
        int o = tid * 32 + i;
        int lane = (o >> 3) & 63, ntp = (o >> 9) & 1, kc = o >> 10;
        int id = lane & 15, quad = lane >> 4;
        __align__(16) unsigned short p[8];
#pragma unroll
        for (int j = 0; j < 8; ++j) p[j] = f2bf(T[ntp * 16 + id][kc * 32 + quad * 8 + j]);
        size_t dsto = ((size_t)((((tile * 8 + kc) * 2 + g) * 4 + (nt0 + ntp)) * 64 + lane)) * 8;
        *(uint4*)(XF + dsto) = *(uint4*)p;
    }
}

// ---------------------------------------------------------------------------
// Prep: head weights -> bf16 fragment-major, via LDS transpose (coalesced).
// Per combo: WF1 [kc(8)][ftile(16)][lane(64)][j(8)] (65536 h), WF2 (+65536),
// WF3 [kc(8)][ftile(4)][lane][j] (+131072).  W1 row 256 -> W1L fp32.
// grid = 32 combos x 24 (st 0/1: kc 0..7 of W1/W2; st 2: kc of W3).
// ---------------------------------------------------------------------------
__global__ __launch_bounds__(256) void prep_w(
    const float* __restrict__ kW1, const float* __restrict__ kW2, const float* __restrict__ kW3,
    const float* __restrict__ vW1, const float* __restrict__ vW2, const float* __restrict__ vW3,
    unsigned short* __restrict__ WP, float* __restrict__ W1L) {
    __shared__ float T[32][257];
    int bid = blockIdx.x;            // 768
    int combo = bid / 24, r = bid % 24;
    int st = r >> 3, kc = r & 7;
    int kvv = combo >> 4, l = (combo >> 3) & 1, h = combo & 7;
    int tid = threadIdx.x;
    unsigned short* dstc = WP + (size_t)combo * 147456;
    if (st < 2) {
        const float* W = (st == 0) ? (kvv ? vW1 : kW1) : (kvv ? vW2 : kW2);
        int rows = (st == 0) ? 257 : 256;
        const float* src = W + ((size_t)(l * 8 + h) * rows + kc * 32) * 256;
#pragma unroll
        for (int it = 0; it < 8; ++it) {
            int f4 = it * 256 + tid;
            int row = f4 >> 6, c = (f4 & 63) * 4;
            float4 v = *(const float4*)(src + (size_t)row * 256 + c);
            T[row][c] = v.x; T[row][c + 1] = v.y; T[row][c + 2] = v.z; T[row][c + 3] = v.w;
        }
        __syncthreads();
        unsigned short* dst = dstc + st * 65536 + kc * 8192;
#pragma unroll
        for (int i = 0; i < 32; i += 8) {
            int o = tid * 32 + i;
            int lane = (o >> 3) & 63, ftile = o >> 9;
            int id = lane & 15, quad = lane >> 4;
            __align__(16) unsigned short p[8];
#pragma unroll
            for (int j = 0; j < 8; ++j) p[j] = f2bf(T[quad * 8 + j][ftile * 16 + id]);
            *(uint4*)(dst + o) = *(uint4*)p;
        }
        if (st == 0 && kc == 0) {
            const float* hw = (kvv ? vW1 : kW1) + (size_t)(l * 8 + h) * 257 * 256;
            W1L[combo * 256 + tid] = hw[65536 + tid];
        }
    } else {
        const float* src = (kvv ? vW3 : kW3) + ((size_t)(l * 8 + h) * 256 + kc * 32) * 64;
#pragma unroll
        for (int it = 0; it < 2; ++it) {
            int f4 = it * 256 + tid;
            int row = f4 >> 4, c = (f4 & 15) * 4;
            float4 v = *(const float4*)(src + (size_t)row * 64 + c);
            T[row][c] = v.x; T[row][c + 1] = v.y; T[row][c + 2] = v.z; T[row][c + 3] = v.w;
        }
        __syncthreads();
        unsigned short* dst = dstc + 131072 + kc * 2048;
        int o = tid * 8;
        int lane = tid & 63, ftile = tid >> 6;
        int id = lane & 15, quad = lane >> 4;
        __align__(16) unsigned short p[8];
#pragma unroll
        for (int j = 0; j < 8; ++j) p[j] = f2bf(T[quad * 8 + j][ftile * 16 + id]);
        *(uint4*)(dst + o) = *(uint4*)p;
    }
}

// ---------------------------------------------------------------------------
// Prep: generic gemm weights -> bf16 fragment-major via LDS transpose.
// per image: [kc(K/32)][ntile(N/16)][lane(64)][j(8)].  Block = (kc, 128 cols).
// grid 368 x 256.
// ---------------------------------------------------------------------------
__global__ __launch_bounds__(256) void prep_wg(
    const float* __restrict__ dsW, const float* __restrict__ ffW1,
    const float* __restrict__ ffW2, const float* __restrict__ deW1,
    const float* __restrict__ deW2, const float* __restrict__ deW3,
    unsigned short* __restrict__ WG) {
    __shared__ float T[32][129];
    int bid = blockIdx.x, tid = threadIdx.x;
    const float* src; int N, kc, ng; size_t base;
    if (bid < 32)       { int lb = bid;       src = dsW;              N = 512; base = 0;       kc = lb >> 2; ng = lb & 3; }
    else if (bid < 96)  { int lb = bid - 32;  src = ffW1;             N = 512; base = 131072;  kc = lb >> 2; ng = lb & 3; }
    else if (bid < 160) { int lb = bid - 96;  src = ffW1 + 262144;    N = 512; base = 393216;  kc = lb >> 2; ng = lb & 3; }
    else if (bid < 224) { int lb = bid - 160; src = ffW2;             N = 512; base = 655360;  kc = lb >> 2; ng = lb & 3; }
    else if (bid < 288) { int lb = bid - 224; src = ffW2 + 262144;    N = 512; base = 917504;  kc = lb >> 2; ng = lb & 3; }
    else if (bid < 320) { int lb = bid - 288; src = deW1;             N = 256; base = 1179648; kc = lb >> 1; ng = lb & 1; }
    else if (bid < 336) { int lb = bid - 320; src = deW2;             N = 256; base = 1310720; kc = lb >> 1; ng = lb & 1; }
    else                { int lb = bid - 336; src = deW3;             N = 512; base = 1376256; kc = lb >> 2; ng = lb & 3; }
    int NTl = N >> 4;
    const float* s = src + (size_t)(kc * 32) * N + ng * 128;
#pragma unroll
    for (int it = 0; it < 4; ++it) {
        int f4 = it * 256 + tid;
        int row = f4 >> 5, c = (f4 & 31) * 4;
        float4 v = *(const float4*)(s + (size_t)row * N + c);
        T[row][c] = v.x; T[row][c + 1] = v.y; T[row][c + 2] = v.z; T[row][c + 3] = v.w;
    }
    __syncthreads();
    unsigned short* d = WG + base + (size_t)(kc * NTl + ng * 8) * 512;
#pragma unroll
    for (int i = 0; i < 16; i += 8) {
        int o = tid * 16 + i;
        int lane = (o >> 3) & 63, ntl = o >> 9;
        int id = lane & 15, quad = lane >> 4;
        __align__(16) unsigned short p[8];
#pragma unroll
        for (int j = 0; j < 8; ++j) p[j] = f2bf(T[quad * 8 + j][ntl * 16 + id]);
        *(uint4*)(d + o) = *(uint4*)p;
    }
}

// ---------------------------------------------------------------------------
// Fused per-head MLP v3: 128-token tiles, 8 waves (g=token-half, w2=f-quarter).
// X tile staged once in LDS (frag layout); W frags direct-global with 1-deep
// double-buffer across kc; H transposes via LDS [128][264]; KV stores staged
// in LDS [128][72] and written as full 128B lines.
// ---------------------------------------------------------------------------
__global__ __launch_bounds__(512, 4) void heads_mlp(
    const float* __restrict__ tu, const unsigned short* __restrict__ XF,
    const unsigned short* __restrict__ WP, const float* __restrict__ W1L,
    const float* __restrict__ kb1, const float* __restrict__ kb2, const float* __restrict__ kb3,
    const float* __restrict__ vb1, const float* __restrict__ vb2, const float* __restrict__ vb3,
    unsigned short* __restrict__ KV) {
    extern __shared__ __align__(16) unsigned short smem[];   // 67584 B

    const int tid = threadIdx.x;
    const int wv = tid >> 6, lane = tid & 63, id = lane & 15, quad = lane >> 4;
    const int g = wv >> 2, w2 = wv & 3;
    const int combo = blockIdx.x & 31, tile = blockIdx.x >> 5;
    const int kvv = combo >> 4, l = (combo >> 3) & 1, h = combo & 7;
    const int r0 = tile * 128;
    const unsigned short* WF1 = WP + (size_t)combo * 147456;
    const unsigned short* WF2 = WF1 + 65536;
    const unsigned short* WF3 = WF1 + 131072;
    const float* b1 = (kvv ? vb1 : kb1) + (l * 8 + h) * 256;
    const float* b2 = (kvv ? vb2 : kb2) + (l * 8 + h) * 256;
    const float* b3 = (kvv ? vb3 : kb3) + (l * 8 + h) * 64;

    // ---- stage X tile (64 KB, frag layout) into LDS ----
    {
        const uint4* s = (const uint4*)(XF + (size_t)tile * 32768);
        uint4* d = (uint4*)smem;
#pragma unroll
        for (int it = 0; it < 8; ++it) d[it * 512 + tid] = s[it * 512 + tid];
    }
    __syncthreads();

    f32x4 acc[4][4];
#pragma unroll
    for (int i = 0; i < 4; ++i)
#pragma unroll
        for (int j = 0; j < 4; ++j) acc[i][j] = (f32x4){0.f, 0.f, 0.f, 0.f};

    // ---------------- stage 1: H1 = relu(X*W1 + b1 + u*w1last) ----------------
    {
        short8 af[4], afn[4];
#pragma unroll
        for (int ft = 0; ft < 4; ++ft)
            af[ft] = *(const short8*)(WF1 + (size_t)((w2 * 4 + ft) * 64 + lane) * 8);
#pragma unroll
        for (int kc = 0; kc < 8; ++kc) {
            if (kc < 7) {
#pragma unroll
                for (int ft = 0; ft < 4; ++ft)
                    afn[ft] = *(const short8*)(WF1 + (size_t)(((kc + 1) * 16 + w2 * 4 + ft) * 64 + lane) * 8);
            }
            const unsigned short* xb = smem + (size_t)((kc * 2 + g) * 4) * 512 + lane * 8;
            short8 bf[4];
#pragma unroll
            for (int nt = 0; nt < 4; ++nt) bf[nt] = *(const short8*)(xb + nt * 512);
#pragma unroll
            for (int ft = 0; ft < 4; ++ft)
#pragma unroll
                for (int nt = 0; nt < 4; ++nt)
                    acc[ft][nt] = __builtin_amdgcn_mfma_f32_16x16x32_bf16(af[ft], bf[nt], acc[ft][nt], 0, 0, 0);
#pragma unroll
            for (int ft = 0; ft < 4; ++ft) af[ft] = afn[ft];
        }
    }
    __syncthreads();   // all X reads done; smem becomes bufH [128][264]
    {
        float ur[4];
#pragma unroll
        for (int nt = 0; nt < 4; ++nt) ur[nt] = tu[r0 + g * 64 + nt * 16 + id];
#pragma unroll
        for (int ft = 0; ft < 4; ++ft) {
            int fb = w2 * 64 + ft * 16 + quad * 4;
            float4 bb = *(const float4*)(b1 + fb);
            float4 wl = *(const float4*)(W1L + combo * 256 + fb);
            const float* bbp = (const float*)&bb;
            const float* wlp = (const float*)&wl;
#pragma unroll
            for (int nt = 0; nt < 4; ++nt) {
                unsigned short p[4];
#pragma unroll
                for (int r = 0; r < 4; ++r) {
                    float v = acc[ft][nt][r] + bbp[r] + ur[nt] * wlp[r];
                    p[r] = f2bf(fmaxf(v, 0.f));
                }
                uint2 pk;
                pk.x = (unsigned)p[0] | ((unsigned)p[1] << 16);
                pk.y = (unsigned)p[2] | ((unsigned)p[3] << 16);
                *(uint2*)(smem + (size_t)(g * 64 + nt * 16 + id) * 264 + fb) = pk;
            }
        }
    }
    __syncthreads();

    // ---------------- stage 2: H2 = relu(H1*W2 + b2) ----------------
#pragma unroll
    for (int i = 0; i < 4; ++i)
#pragma unroll
        for (int j = 0; j < 4; ++j) acc[i][j] = (f32x4){0.f, 0.f, 0.f, 0.f};
    {
        short8 af[4], afn[4];
#pragma unroll
        for (int ft = 0; ft < 4; ++ft)
            af[ft] = *(const short8*)(WF2 + (size_t)((w2 * 4 + ft) * 64 + lane) * 8);
#pragma unroll
        for (int kc = 0; kc < 8; ++kc) {
            if (kc < 7) {
#pragma unroll
                for (int ft = 0; ft < 4; ++ft)
                    afn[ft] = *(const short8*)(WF2 + (size_t)(((kc + 1) * 16 + w2 * 4 + ft) * 64 + lane) * 8);
            }
            short8 bf[4];
#pragma unroll
            for (int nt = 0; nt < 4; ++nt)
                bf[nt] = *(const short8*)(smem + (size_t)(g * 64 + nt * 16 + id) * 264 + kc * 32 + quad * 8);
#pragma unroll
            for (int ft = 0; ft < 4; ++ft)
#pragma unroll
                for (int nt = 0; nt < 4; ++nt)
                    acc[ft][nt] = __builtin_amdgcn_mfma_f32_16x16x32_bf16(af[ft], bf[nt], acc[ft][nt], 0, 0, 0);
#pragma unroll
            for (int ft = 0; ft < 4; ++ft) af[ft] = afn[ft];
        }
    }
    __syncthreads();   // all H1 reads done before overwrite
#pragma unroll
    for (int ft = 0; ft < 4; ++ft) {
        int fb = w2 * 64 + ft * 16 + quad * 4;
        float4 bb = *(const float4*)(b2 + fb);
        const float* bbp = (const float*)&bb;
#pragma unroll
        for (int nt = 0; nt < 4; ++nt) {
            unsigned short p[4];
#pragma unroll
            for (int r = 0; r < 4; ++r)
                p[r] = f2bf(fmaxf(acc[ft][nt][r] + bbp[r], 0.f));
            uint2 pk;
            pk.x = (unsigned)p[0] | ((unsigned)p[1] << 16);
            pk.y = (unsigned)p[2] | ((unsigned)p[3] << 16);
            *(uint2*)(smem + (size_t)(g * 64 + nt * 16 + id) * 264 + fb) = pk;
        }
    }
    __syncthreads();

    // ---------------- stage 3: OUT = H2*W3 + b3 (dk=64), wave = 16 tokens ----
    f32x4 a3[4];
#pragma unroll
    for (int i = 0; i < 4; ++i) a3[i] = (f32x4){0.f, 0.f, 0.f, 0.f};
    {
        short8 af3[4], af3n[4];
#pragma unroll
        for (int ft = 0; ft < 4; ++ft)
            af3[ft] = *(const short8*)(WF3 + (size_t)(ft * 64 + lane) * 8);
#pragma unroll
        for (int kc = 0; kc < 8; ++kc) {
            if (kc < 7) {
#pragma unroll
                for (int ft = 0; ft < 4; ++ft)
                    af3n[ft] = *(const short8*)(WF3 + (size_t)(((kc + 1) * 4 + ft) * 64 + lane) * 8);
            }
            short8 b3f = *(const short8*)(smem + (size_t)(wv * 16 + id) * 264 + kc * 32 + quad * 8);
#pragma unroll
            for (int ft = 0; ft < 4; ++ft)
                a3[ft] = __builtin_amdgcn_mfma_f32_16x16x32_bf16(af3[ft], b3f, a3[ft], 0, 0, 0);
#pragma unroll
            for (int ft = 0; ft < 4; ++ft) af3[ft] = af3n[ft];
        }
    }
    __syncthreads();   // H2 reads done; smem becomes KV staging [128][72]
    {
        int tl = wv * 16 + id;
#pragma unroll
        for (int ft = 0; ft < 4; ++ft) {
            int dk0 = ft * 16 + quad * 4;
            float4 bb = *(const float4*)(b3 + dk0);
            const float* bbp = (const float*)&bb;
            unsigned short p[4];
#pragma unroll
            for (int r = 0; r < 4; ++r) p[r] = f2bf(a3[ft][r] + bbp[r]);
            uint2 pk;
            pk.x = (unsigned)p[0] | ((unsigned)p[1] << 16);
            pk.y = (unsigned)p[2] | ((unsigned)p[3] << 16);
            *(uint2*)(smem + (size_t)tl * 72 + dk0) = pk;
        }
    }
    __syncthreads();
    {
#pragma unroll
        for (int it = 0; it < 2; ++it) {
            int tl = it * 64 + (tid >> 3), part = tid & 7;
            uint4 v = *(const uint4*)(smem + (size_t)tl * 72 + part * 8);
            size_t base = ((size_t)((l * 2 + kvv) * NTOK + r0 + tl)) * 512 + h * 64 + part * 8;
            *(uint4*)(KV + base) = v;
        }
    }
}

// ---------------------------------------------------------------------------
// pred = encoded[:, i, mid_idx]  -> bf16 PREDB (1024 x 256)
// ---------------------------------------------------------------------------
__global__ __launch_bounds__(64) void gather_pred(const float* __restrict__ enc,
                                                  const int* __restrict__ mid,
                                                  const int* __restrict__ ip,
                                                  unsigned short* __restrict__ predb) {
    int row = blockIdx.x;  // b*128+m
    int b = row >> 7, m = row & 127;
    int iv = ip[0];
    int t = mid[m];
    const float* src = enc + (((size_t)(b * NS + iv)) * NT + t) * ND;
    float4 v = *(const float4*)(src + threadIdx.x * 4);
    uint2 pk;
    pk.x = (unsigned)f2bf(v.x) | ((unsigned)f2bf(v.y) << 16);
    pk.y = (unsigned)f2bf(v.z) | ((unsigned)f2bf(v.w) << 16);
    *(uint2*)(predb + (size_t)row * ND + threadIdx.x * 4) = pk;
}

// ---------------------------------------------------------------------------
// bf16 MFMA gemm with 1-deep prefetch:
// out = [relu](A[1024xK]bf16 @ W[KxN]bf16 + bias [+ res_f32])
// grid (N/64, 32), block 256: wave = 1 ntile x 2 mtiles (32 rows).
// ---------------------------------------------------------------------------
__global__ __launch_bounds__(256) void gemm_bf16(
    const unsigned short* __restrict__ A, const unsigned short* __restrict__ WF,
    const float* __restrict__ bias, const float* __restrict__ res,
    float* __restrict__ outf, unsigned short* __restrict__ outb,
    int K, int N, int relu) {
    int tid = threadIdx.x, wv = tid >> 6, lane = tid & 63;
    int id = lane & 15, quad = lane >> 4;
    int ntile = blockIdx.x * 4 + wv;
    int n0 = ntile * 16, m0 = blockIdx.y * 32;
    int NTl = N >> 4, KC = K >> 5;
    f32x4 acc[2];
    acc[0] = (f32x4){0.f, 0.f, 0.f, 0.f};
    acc[1] = (f32x4){0.f, 0.f, 0.f, 0.f};
    short8 bw = *(const short8*)(WF + (size_t)(ntile * 64 + lane) * 8);
    short8 a0 = *(const short8*)(A + (size_t)(m0 + id) * K + quad * 8);
    short8 a1 = *(const short8*)(A + (size_t)(m0 + 16 + id) * K + quad * 8);
    for (int kc = 0; kc < KC; ++kc) {
        short8 bwn, a0n, a1n;
        if (kc + 1 < KC) {
            bwn = *(const short8*)(WF + (size_t)(((kc + 1) * NTl + ntile) * 64 + lane) * 8);
            a0n = *(const short8*)(A + (size_t)(m0 + id) * K + (kc + 1) * 32 + quad * 8);
            a1n = *(const short8*)(A + (size_t)(m0 + 16 + id) * K + (kc + 1) * 32 + quad * 8);
        }
        acc[0] = __builtin_amdgcn_mfma_f32_16x16x32_bf16(a0, bw, acc[0], 0, 0, 0);
        acc[1] = __builtin_amdgcn_mfma_f32_16x16x32_bf16(a1, bw, acc[1], 0, 0, 0);
        bw = bwn; a0 = a0n; a1 = a1n;
    }
    float bv = bias[n0 + id];
#pragma unroll
    for (int mt = 0; mt < 2; ++mt) {
#pragma unroll
        for (int r = 0; r < 4; ++r) {
            int row = m0 + mt * 16 + quad * 4 + r;
            int n = n0 + id;
            float v = acc[mt][r] + bv;
            if (res) v += res[(size_t)row * N + n];
            if (relu) v = fmaxf(v, 0.f);
            if (outf) outf[(size_t)row * N + n] = v;
            if (outb) outb[(size_t)row * N + n] = f2bf(v);
        }
    }
}

// ---------------------------------------------------------------------------
// Attention (2 neighbors, softmax over n, sum over s) + residual + LN1.
// One wave per (b,m) row.  grid 256 x 256 thr.  fp32 out + bf16 out.
// ---------------------------------------------------------------------------
__global__ __launch_bounds__(256) void attn_ln(
    const float* __restrict__ attv, const unsigned short* __restrict__ keys,
    const unsigned short* __restrict__ vals, const int* __restrict__ left,
    const int* __restrict__ right, const int* __restrict__ ip,
    const float* __restrict__ g, const float* __restrict__ bb,
    float* __restrict__ xout, unsigned short* __restrict__ xoutb) {
    int tid = threadIdx.x, wv = tid >> 6, lane = tid & 63;
    int gid = blockIdx.x * 4 + wv;  // 0..1023 = b*128+m
    int b = gid >> 7, m = gid & 127;
    int iv = ip[0];
    int lt = left[m], rt = right[m];
    float av[8], att[8];
#pragma unroll
    for (int h = 0; h < 8; ++h) {
        av[h] = attv[(size_t)gid * 512 + h * 64 + lane];
        att[h] = 0.f;
    }
    for (int s = 0; s < 8; ++s) {
        int t1 = (s < iv) ? m : rt;
        size_t o0 = ((size_t)((b * 8 + s) * 256 + lt)) * 512 + lane;
        size_t o1 = ((size_t)((b * 8 + s) * 256 + t1)) * 512 + lane;
#pragma unroll
        for (int h = 0; h < 8; ++h) {
            float k0 = bf2f(keys[o0 + h * 64]);
            float k1 = bf2f(keys[o1 + h * 64]);
            float p0 = wred(av[h] * k0) * 0.125f;
            float p1 = wred(av[h] * k1) * 0.125f;
            float mx = fmaxf(p0, p1);
            float e0 = expf(p0 - mx), e1 = expf(p1 - mx);
            float inv = 1.f / (e0 + e1);
            float w0 = e0 * inv, w1 = e1 * inv;
            float v0 = bf2f(vals[o0 + h * 64]);
            float v1 = bf2f(vals[o1 + h * 64]);
            att[h] += w0 * v0 + w1 * v1;
        }
    }
    float xp[8], sum = 0.f;
#pragma unroll
    for (int h = 0; h < 8; ++h) { xp[h] = av[h] + att[h]; sum += xp[h]; }
    float mu = wred(sum) * (1.f / 512.f);
    float s2 = 0.f;
#pragma unroll
    for (int h = 0; h < 8; ++h) { float d = xp[h] - mu; s2 += d * d; }
    float rs = rsqrtf(wred(s2) * (1.f / 512.f) + 1e-5f);
#pragma unroll
    for (int h = 0; h < 8; ++h) {
        float v = (xp[h] - mu) * rs * g[h * 64 + lane] + bb[h * 64 + lane];
        xout[(size_t)gid * 512 + h * 64 + lane] = v;
        xoutb[(size_t)gid * 512 + h * 64 + lane] = f2bf(v);
    }
}

// ---------------------------------------------------------------------------
// LayerNorm over 512, one wave per row. fp32 out + bf16 out.
// ---------------------------------------------------------------------------
__global__ __launch_bounds__(256) void ln_k(const float* __restrict__ in,
                                            const float* __restrict__ g,
                                            const float* __restrict__ bb,
                                            float* __restrict__ out,
                                            unsigned short* __restrict__ outb) {
    int tid = threadIdx.x, wv = tid >> 6, lane = tid & 63;
    int gid = blockIdx.x * 4 + wv;
    float x[8], sum = 0.f;
#pragma unroll
    for (int h = 0; h < 8; ++h) { x[h] = in[(size_t)gid * 512 + h * 64 + lane]; sum += x[h]; }
    float mu = wred(sum) * (1.f / 512.f);
    float s2 = 0.f;
#pragma unroll
    for (int h = 0; h < 8; ++h) { float d = x[h] - mu; s2 += d * d; }
    float rs = rsqrtf(wred(s2) * (1.f / 512.f) + 1e-5f);
#pragma unroll
    for (int h = 0; h < 8; ++h) {
        float v = (x[h] - mu) * rs * g[h * 64 + lane] + bb[h * 64 + lane];
        out[(size_t)gid * 512 + h * 64 + lane] = v;
        outb[(size_t)gid * 512 + h * 64 + lane] = f2bf(v);
    }
}

// ---------------------------------------------------------------------------
extern "C" void kernel_launch(void* const* d_in, const int* in_sizes, int n_in,
                              void* d_out, int out_size, void* d_ws, size_t ws_size,
                              hipStream_t stream) {
    const float* encoded = (const float*)d_in[0];
    const float* true_u  = (const float*)d_in[1];
    const int* mid_idx   = (const int*)d_in[2];
    const int* left_idx  = (const int*)d_in[3];
    const int* right_idx = (const int*)d_in[4];
    const int* ip        = (const int*)d_in[5];
    const float* ds_W = (const float*)d_in[6];
    const float* ds_b = (const float*)d_in[7];
    const float* kW1 = (const float*)d_in[8];
    const float* kb1 = (const float*)d_in[9];
    const float* kW2 = (const float*)d_in[10];
    const float* kb2 = (const float*)d_in[11];
    const float* kW3 = (const float*)d_in[12];
    const float* kb3 = (const float*)d_in[13];
    const float* vW1 = (const float*)d_in[14];
    const float* vb1 = (const float*)d_in[15];
    const float* vW2 = (const float*)d_in[16];
    const float* vb2 = (const float*)d_in[17];
    const float* vW3 = (const float*)d_in[18];
    const float* vb3 = (const float*)d_in[19];
    const float* ln1_g = (const float*)d_in[20];
    const float* ln1_b = (const float*)d_in[21];
    const float* ln2_g = (const float*)d_in[22];
    const float* ln2_b = (const float*)d_in[23];
    const float* ffW1 = (const float*)d_in[24];
    const float* ffb1 = (const float*)d_in[25];
    const float* ffW2 = (const float*)d_in[26];
    const float* ffb2 = (const float*)d_in[27];
    const float* deW1 = (const float*)d_in[28];
    const float* deb1 = (const float*)d_in[29];
    const float* deW2 = (const float*)d_in[30];
    const float* deb2 = (const float*)d_in[31];
    const float* deW3 = (const float*)d_in[32];
    const float* deb3 = (const float*)d_in[33];

    char* ws = (char*)d_ws;
    unsigned short* XF   = (unsigned short*)(ws + 0);          //  8,388,608
    unsigned short* WP   = (unsigned short*)(ws + 8388608);    //  9,437,184
    float* W1L           = (float*)(ws + 17825792);            //     32,768
    unsigned short* KV   = (unsigned short*)(ws + 17858560);   // 67,108,864
    unsigned short* WG   = (unsigned short*)(ws + 84967424);   //  3,014,656
    float* ATTV          = (float*)(ws + 87982080);            //  2,097,152
    float* XBUF          = (float*)(ws + 90079232);            //  2,097,152
    float* YBUF          = (float*)(ws + 92176384);            //  2,097,152
    unsigned short* PREDB = (unsigned short*)(ws + 94273536);  //    524,288
    unsigned short* ATTVB = (unsigned short*)(ws + 94797824);  //  1,048,576
    unsigned short* XBUFB = (unsigned short*)(ws + 95846400);  //  1,048,576
    unsigned short* FBUFB = (unsigned short*)(ws + 96894976);  //  1,048,576 (end 97,943,552)
    unsigned short* DE1B = XBUFB;   // reuse (free after layers)
    unsigned short* DE2B = FBUFB;

    // WG image offsets (halves)
    unsigned short* WGds  = WG + 0;
    unsigned short* WGff1_0 = WG + 131072;
    unsigned short* WGff1_1 = WG + 393216;
    unsigned short* WGff2_0 = WG + 655360;
    unsigned short* WGff2_1 = WG + 917504;
    unsigned short* WGde1 = WG + 1179648;
    unsigned short* WGde2 = WG + 1310720;
    unsigned short* WGde3 = WG + 1376256;

    prep_x<<<512, 256, 0, stream>>>(encoded, XF);
    prep_w<<<768, 256, 0, stream>>>(kW1, kW2, kW3, vW1, vW2, vW3, WP, W1L);
    prep_wg<<<368, 256, 0, stream>>>(ds_W, ffW1, ffW2, deW1, deW2, deW3, WG);
    heads_mlp<<<4096, 512, 67584, stream>>>(true_u, XF, WP, W1L, kb1, kb2, kb3,
                                            vb1, vb2, vb3, KV);
    gather_pred<<<1024, 64, 0, stream>>>(encoded, mid_idx, ip, PREDB);
    gemm_bf16<<<dim3(8, 32), 256, 0, stream>>>(PREDB, WGds, ds_b, nullptr,
                                               ATTV, nullptr, 256, 512, 0);
    for (int l = 0; l < 2; ++l) {
        const unsigned short* keys = KV + (size_t)(l * 2) * NTOK * NHD;
        const unsigned short* vals = KV + (size_t)(l * 2 + 1) * NTOK * NHD;
        attn_ln<<<256, 256, 0, stream>>>(ATTV, keys, vals, left_idx, right_idx, ip,
                                         ln1_g + l * 512, ln1_b + l * 512, XBUF, XBUFB);
        gemm_bf16<<<dim3(8, 32), 256, 0, stream>>>(XBUFB, (l ? WGff1_1 : WGff1_0),
                                                   ffb1 + l * 512, nullptr,
                                                   nullptr, FBUFB, 512, 512, 1);
        gemm_bf16<<<dim3(8, 32), 256, 0, stream>>>(FBUFB, (l ? WGff2_1 : WGff2_0),
                                                   ffb2 + l * 512, XBUF,
                                                   YBUF, nullptr, 512, 512, 0);
        ln_k<<<256, 256, 0, stream>>>(YBUF, ln2_g + l * 512, ln2_b + l * 512, ATTV, ATTVB);
    }
    gemm_bf16<<<dim3(4, 32), 256, 0, stream>>>(ATTVB, WGde1, deb1, nullptr,
                                               nullptr, DE1B, 512, 256, 1);
    gemm_bf16<<<dim3(4, 32), 256, 0, stream>>>(DE1B, WGde2, deb2, nullptr,
                                               nullptr, DE2B, 256, 256, 1);
    gemm_bf16<<<dim3(8, 32), 256, 0, stream>>>(DE2B, WGde3, deb3, nullptr,
                                               (float*)d_out, nullptr, 256, 512, 0);
}

// Round 4
// 431.008 us; speedup vs baseline: 1.8633x; 1.1934x over previous
//
#include <hip/hip_runtime.h>
#include <hip/hip_bf16.h>

// Problem constants
#define NB 8
#define NS 8
#define NT 256
#define ND 256
#define NH 8
#define NDK 64
#define NHD 512
#define NL 2
#define NF 256
#define NR 512
#define NM 128
#define NTOK 16384   // B*S*T
#define NROW 1024    // B*M

typedef __attribute__((ext_vector_type(8))) short short8;
typedef __attribute__((ext_vector_type(4))) float f32x4;

__device__ __forceinline__ unsigned short f2bf(float x) {
    unsigned u = __builtin_bit_cast(unsigned, x);
    unsigned r = (u + 0x7fffu + ((u >> 16) & 1u)) >> 16;
    return (unsigned short)r;
}
__device__ __forceinline__ float bf2f(unsigned short x) {
    return __builtin_bit_cast(float, ((unsigned)x) << 16);
}
__device__ __forceinline__ float wred(float v) {
#pragma unroll
    for (int o = 32; o > 0; o >>= 1) v += __shfl_xor(v, o, 64);
    return v;
}

// ---------------------------------------------------------------------------
// Merged prep kernel.  Grid 1648 blocks:
//  [0,512):    encoded fp32 -> XF bf16 fragment-major (32-token LDS transpose)
//  [512,1280): head weights -> WP fragment-major images + W1L
//  [1280,1648): ds/ff/de weights -> WG fragment-major images
// XF layout: [tile128][kc(8)][g(2)][nt(4)][lane(64)][j(8)]
// WP per combo: WF1 [kc][ftile16][lane][8], WF2 +65536, WF3 [kc][ftile4][lane][8] +131072
// WG per image: [kc][ntile][lane][8]
// ---------------------------------------------------------------------------
__global__ __launch_bounds__(256) void prep_all(
    const float* __restrict__ enc,
    const float* __restrict__ kW1, const float* __restrict__ kW2, const float* __restrict__ kW3,
    const float* __restrict__ vW1, const float* __restrict__ vW2, const float* __restrict__ vW3,
    const float* __restrict__ dsW, const float* __restrict__ ffW1,
    const float* __restrict__ ffW2, const float* __restrict__ deW1,
    const float* __restrict__ deW2, const float* __restrict__ deW3,
    unsigned short* __restrict__ XF, unsigned short* __restrict__ WP,
    float* __restrict__ W1L, unsigned short* __restrict__ WG) {
    __shared__ float T[32][257];
    int bid = blockIdx.x, tid = threadIdx.x;
    if (bid < 512) {
        // ---------------- prep_x ----------------
        int t0 = bid * 32;
        const float* src = enc + (size_t)t0 * 256;
#pragma unroll
        for (int it = 0; it < 8; ++it) {
            int f4 = it * 256 + tid;
            int row = f4 >> 6, c = (f4 & 63) * 4;
            float4 v = *(const float4*)(src + row * 256 + c);
            T[row][c] = v.x; T[row][c + 1] = v.y; T[row][c + 2] = v.z; T[row][c + 3] = v.w;
        }
        __syncthreads();
        int tile = t0 >> 7, g = (t0 >> 6) & 1, nt0 = (t0 >> 4) & 3;
#pragma unroll
        for (int i = 0; i < 32; i += 8) {
            int o = tid * 32 + i;
            int lane = (o >> 3) & 63, ntp = (o >> 9) & 1, kc = o >> 10;
            int id = lane & 15, quad = lane >> 4;
            __align__(16) unsigned short p[8];
#pragma unroll
            for (int j = 0; j < 8; ++j) p[j] = f2bf(T[ntp * 16 + id][kc * 32 + quad * 8 + j]);
            size_t dsto = ((size_t)((((tile * 8 + kc) * 2 + g) * 4 + (nt0 + ntp)) * 64 + lane)) * 8;
            *(uint4*)(XF + dsto) = *(uint4*)p;
        }
    } else if (bid < 1280) {
        // ---------------- prep_w ----------------
        int lb = bid - 512;               // 768
        int combo = lb / 24, r = lb % 24;
        int st = r >> 3, kc = r & 7;
        int kvv = combo >> 4, l = (combo >> 3) & 1, h = combo & 7;
        unsigned short* dstc = WP + (size_t)combo * 147456;
        if (st < 2) {
            const float* W = (st == 0) ? (kvv ? vW1 : kW1) : (kvv ? vW2 : kW2);
            int rows = (st == 0) ? 257 : 256;
            const float* src = W + ((size_t)(l * 8 + h) * rows + kc * 32) * 256;
#pragma unroll
            for (int it = 0; it < 8; ++it) {
                int f4 = it * 256 + tid;
                int row = f4 >> 6, c = (f4 & 63) * 4;
                float4 v = *(const float4*)(src + (size_t)row * 256 + c);
                T[row][c] = v.x; T[row][c + 1] = v.y; T[row][c + 2] = v.z; T[row][c + 3] = v.w;
            }
            __syncthreads();
            unsigned short* dst = dstc + st * 65536 + kc * 8192;
#pragma unroll
            for (int i = 0; i < 32; i += 8) {
                int o = tid * 32 + i;
                int lane = (o >> 3) & 63, ftile = o >> 9;
                int id = lane & 15, quad = lane >> 4;
                __align__(16) unsigned short p[8];
#pragma unroll
                for (int j = 0; j < 8; ++j) p[j] = f2bf(T[quad * 8 + j][ftile * 16 + id]);
                *(uint4*)(dst + o) = *(uint4*)p;
            }
            if (st == 0 && kc == 0) {
                const float* hw = (kvv ? vW1 : kW1) + (size_t)(l * 8 + h) * 257 * 256;
                W1L[combo * 256 + tid] = hw[65536 + tid];
            }
        } else {
            const float* src = (kvv ? vW3 : kW3) + ((size_t)(l * 8 + h) * 256 + kc * 32) * 64;
#pragma unroll
            for (int it = 0; it < 2; ++it) {
                int f4 = it * 256 + tid;
                int row = f4 >> 4, c = (f4 & 15) * 4;
                float4 v = *(const float4*)(src + (size_t)row * 64 + c);
                T[row][c] = v.x; T[row][c + 1] = v.y; T[row][c + 2] = v.z; T[row][c + 3] = v.w;
            }
            __syncthreads();
            unsigned short* dst = dstc + 131072 + kc * 2048;
            int o = tid * 8;
            int lane = tid & 63, ftile = tid >> 6;
            int id = lane & 15, quad = lane >> 4;
            __align__(16) unsigned short p[8];
#pragma unroll
            for (int j = 0; j < 8; ++j) p[j] = f2bf(T[quad * 8 + j][ftile * 16 + id]);
            *(uint4*)(dst + o) = *(uint4*)p;
        }
    } else {
        // ---------------- prep_wg ----------------
        int lb0 = bid - 1280;             // 368
        const float* src; int N, kc, ng; size_t base;
        if (lb0 < 32)       { int lb = lb0;       src = dsW;           N = 512; base = 0;       kc = lb >> 2; ng = lb & 3; }
        else if (lb0 < 96)  { int lb = lb0 - 32;  src = ffW1;          N = 512; base = 131072;  kc = lb >> 2; ng = lb & 3; }
        else if (lb0 < 160) { int lb = lb0 - 96;  src = ffW1 + 262144; N = 512; base = 393216;  kc = lb >> 2; ng = lb & 3; }
        else if (lb0 < 224) { int lb = lb0 - 160; src = ffW2;          N = 512; base = 655360;  kc = lb >> 2; ng = lb & 3; }
        else if (lb0 < 288) { int lb = lb0 - 224; src = ffW2 + 262144; N = 512; base = 917504;  kc = lb >> 2; ng = lb & 3; }
        else if (lb0 < 320) { int lb = lb0 - 288; src = deW1;          N = 256; base = 1179648; kc = lb >> 1; ng = lb & 1; }
        else if (lb0 < 336) { int lb = lb0 - 320; src = deW2;          N = 256; base = 1310720; kc = lb >> 1; ng = lb & 1; }
        else                { int lb = lb0 - 336; src = deW3;          N = 512; base = 1376256; kc = lb >> 2; ng = lb & 3; }
        int NTl = N >> 4;
        const float* s = src + (size_t)(kc * 32) * N + ng * 128;
#pragma unroll
        for (int it = 0; it < 4; ++it) {
            int f4 = it * 256 + tid;
            int row = f4 >> 5, c = (f4 & 31) * 4;
            float4 v = *(const float4*)(s + (size_t)row * N + c);
            T[row][c] = v.x; T[row][c + 1] = v.y; T[row][c + 2] = v.z; T[row][c + 3] = v.w;
        }
        __syncthreads();
        unsigned short* d = WG + base + (size_t)(kc * NTl + ng * 8) * 512;
#pragma unroll
        for (int i = 0; i < 16; i += 8) {
            int o = tid * 16 + i;
            int lane = (o >> 3) & 63, ntl = o >> 9;
            int id = lane & 15, quad = lane >> 4;
            __align__(16) unsigned short p[8];
#pragma unroll
            for (int j = 0; j < 8; ++j) p[j] = f2bf(T[quad * 8 + j][ntl * 16 + id]);
            *(uint4*)(d + o) = *(uint4*)p;
        }
    }
}

// ---------------------------------------------------------------------------
// Fused per-head MLP v4: 64-token tiles, 256 threads (4 waves = f-quarters),
// 33.8 KB LDS -> 4 blocks/CU for latency hiding.  X tile staged once in LDS
// (frag layout, overlaid by H buffer); W frags direct-global with 1-deep
// prefetch; KV stores staged in LDS and written as full 128B lines.
// grid = tile*32 + combo (combo%8 pins a combo's W to one XCD's L2).
// ---------------------------------------------------------------------------
__global__ __launch_bounds__(256, 4) void heads_mlp(
    const float* __restrict__ tu, const unsigned short* __restrict__ XF,
    const unsigned short* __restrict__ WP, const float* __restrict__ W1L,
    const float* __restrict__ kb1, const float* __restrict__ kb2, const float* __restrict__ kb3,
    const float* __restrict__ vb1, const float* __restrict__ vb2, const float* __restrict__ vb3,
    unsigned short* __restrict__ KV) {
    __shared__ __align__(16) unsigned short smem[16896];   // 33792 B

    const int tid = threadIdx.x;
    const int w2 = tid >> 6, lane = tid & 63, id = lane & 15, quad = lane >> 4;
    const int combo = blockIdx.x & 31, t64 = blockIdx.x >> 5;   // 0..255
    const int kvv = combo >> 4, l = (combo >> 3) & 1, h = combo & 7;
    const int r0 = t64 * 64;
    const int tile128 = t64 >> 1, g = t64 & 1;
    const unsigned short* WF1 = WP + (size_t)combo * 147456;
    const unsigned short* WF2 = WF1 + 65536;
    const unsigned short* WF3 = WF1 + 131072;
    const float* b1 = (kvv ? vb1 : kb1) + (l * 8 + h) * 256;
    const float* b2 = (kvv ? vb2 : kb2) + (l * 8 + h) * 256;
    const float* b3 = (kvv ? vb3 : kb3) + (l * 8 + h) * 64;

    // ---- stage X tile (32 KB, frag layout [kc][nt][lane][8]) into LDS ----
    {
        const uint4* s = (const uint4*)(XF + (size_t)tile128 * 32768 + g * 2048);
        uint4* d = (uint4*)smem;
#pragma unroll
        for (int kc = 0; kc < 8; ++kc) d[kc * 256 + tid] = s[kc * 512 + tid];
    }
    __syncthreads();

    f32x4 acc[4][4];
#pragma unroll
    for (int i = 0; i < 4; ++i)
#pragma unroll
        for (int j = 0; j < 4; ++j) acc[i][j] = (f32x4){0.f, 0.f, 0.f, 0.f};

    // ---------------- stage 1: H1 = relu(X*W1 + b1 + u*w1last) ----------------
    {
        short8 af[4], afn[4];
#pragma unroll
        for (int ft = 0; ft < 4; ++ft)
            af[ft] = *(const short8*)(WF1 + (size_t)((w2 * 4 + ft) * 64 + lane) * 8);
#pragma unroll
        for (int kc = 0; kc < 8; ++kc) {
            if (kc < 7) {
#pragma unroll
                for (int ft = 0; ft < 4; ++ft)
                    afn[ft] = *(const short8*)(WF1 + (size_t)(((kc + 1) * 16 + w2 * 4 + ft) * 64 + lane) * 8);
            }
            short8 bf[4];
#pragma unroll
            for (int nt = 0; nt < 4; ++nt)
                bf[nt] = *(const short8*)(smem + (size_t)(kc * 4 + nt) * 512 + lane * 8);
#pragma unroll
            for (int ft = 0; ft < 4; ++ft)
#pragma unroll
                for (int nt = 0; nt < 4; ++nt)
                    acc[ft][nt] = __builtin_amdgcn_mfma_f32_16x16x32_bf16(af[ft], bf[nt], acc[ft][nt], 0, 0, 0);
#pragma unroll
            for (int ft = 0; ft < 4; ++ft) af[ft] = afn[ft];
        }
    }
    __syncthreads();   // all X reads done; smem becomes bufH [64][264]
    {
        float ur[4];
#pragma unroll
        for (int nt = 0; nt < 4; ++nt) ur[nt] = tu[r0 + nt * 16 + id];
#pragma unroll
        for (int ft = 0; ft < 4; ++ft) {
            int fb = w2 * 64 + ft * 16 + quad * 4;
            float4 bb = *(const float4*)(b1 + fb);
            float4 wl = *(const float4*)(W1L + combo * 256 + fb);
            const float* bbp = (const float*)&bb;
            const float* wlp = (const float*)&wl;
#pragma unroll
            for (int nt = 0; nt < 4; ++nt) {
                unsigned short p[4];
#pragma unroll
                for (int r = 0; r < 4; ++r) {
                    float v = acc[ft][nt][r] + bbp[r] + ur[nt] * wlp[r];
                    p[r] = f2bf(fmaxf(v, 0.f));
                }
                uint2 pk;
                pk.x = (unsigned)p[0] | ((unsigned)p[1] << 16);
                pk.y = (unsigned)p[2] | ((unsigned)p[3] << 16);
                *(uint2*)(smem + (size_t)(nt * 16 + id) * 264 + fb) = pk;
            }
        }
    }
    __syncthreads();

    // ---------------- stage 2: H2 = relu(H1*W2 + b2) ----------------
#pragma unroll
    for (int i = 0; i < 4; ++i)
#pragma unroll
        for (int j = 0; j < 4; ++j) acc[i][j] = (f32x4){0.f, 0.f, 0.f, 0.f};
    {
        short8 af[4], afn[4];
#pragma unroll
        for (int ft = 0; ft < 4; ++ft)
            af[ft] = *(const short8*)(WF2 + (size_t)((w2 * 4 + ft) * 64 + lane) * 8);
#pragma unroll
        for (int kc = 0; kc < 8; ++kc) {
            if (kc < 7) {
#pragma unroll
                for (int ft = 0; ft < 4; ++ft)
                    afn[ft] = *(const short8*)(WF2 + (size_t)(((kc + 1) * 16 + w2 * 4 + ft) * 64 + lane) * 8);
            }
            short8 bf[4];
#pragma unroll
            for (int nt = 0; nt < 4; ++nt)
                bf[nt] = *(const short8*)(smem + (size_t)(nt * 16 + id) * 264 + kc * 32 + quad * 8);
#pragma unroll
            for (int ft = 0; ft < 4; ++ft)
#pragma unroll
                for (int nt = 0; nt < 4; ++nt)
                    acc[ft][nt] = __builtin_amdgcn_mfma_f32_16x16x32_bf16(af[ft], bf[nt], acc[ft][nt], 0, 0, 0);
#pragma unroll
            for (int ft = 0; ft < 4; ++ft) af[ft] = afn[ft];
        }
    }
    __syncthreads();   // all H1 reads done before overwrite
#pragma unroll
    for (int ft = 0; ft < 4; ++ft) {
        int fb = w2 * 64 + ft * 16 + quad * 4;
        float4 bb = *(const float4*)(b2 + fb);
        const float* bbp = (const float*)&bb;
#pragma unroll
        for (int nt = 0; nt < 4; ++nt) {
            unsigned short p[4];
#pragma unroll
            for (int r = 0; r < 4; ++r)
                p[r] = f2bf(fmaxf(acc[ft][nt][r] + bbp[r], 0.f));
            uint2 pk;
            pk.x = (unsigned)p[0] | ((unsigned)p[1] << 16);
            pk.y = (unsigned)p[2] | ((unsigned)p[3] << 16);
            *(uint2*)(smem + (size_t)(nt * 16 + id) * 264 + fb) = pk;
        }
    }
    __syncthreads();

    // ---------------- stage 3: OUT = H2*W3 + b3 (dk=64), wave = 16 tokens ----
    f32x4 a3[4];
#pragma unroll
    for (int i = 0; i < 4; ++i) a3[i] = (f32x4){0.f, 0.f, 0.f, 0.f};
    {
        short8 af3[4], af3n[4];
#pragma unroll
        for (int ft = 0; ft < 4; ++ft)
            af3[ft] = *(const short8*)(WF3 + (size_t)(ft * 64 + lane) * 8);
#pragma unroll
        for (int kc = 0; kc < 8; ++kc) {
            if (kc < 7) {
#pragma unroll
                for (int ft = 0; ft < 4; ++ft)
                    af3n[ft] = *(const short8*)(WF3 + (size_t)(((kc + 1) * 4 + ft) * 64 + lane) * 8);
            }
            short8 b3f = *(const short8*)(smem + (size_t)(w2 * 16 + id) * 264 + kc * 32 + quad * 8);
#pragma unroll
            for (int ft = 0; ft < 4; ++ft)
                a3[ft] = __builtin_amdgcn_mfma_f32_16x16x32_bf16(af3[ft], b3f, a3[ft], 0, 0, 0);
#pragma unroll
            for (int ft = 0; ft < 4; ++ft) af3[ft] = af3n[ft];
        }
    }
    __syncthreads();   // H2 reads done; smem becomes KV staging [64][72]
    {
        int tl = w2 * 16 + id;
#pragma unroll
        for (int ft = 0; ft < 4; ++ft) {
            int dk0 = ft * 16 + quad * 4;
            float4 bb = *(const float4*)(b3 + dk0);
            const float* bbp = (const float*)&bb;
            unsigned short p[4];
#pragma unroll
            for (int r = 0; r < 4; ++r) p[r] = f2bf(a3[ft][r] + bbp[r]);
            uint2 pk;
            pk.x = (unsigned)p[0] | ((unsigned)p[1] << 16);
            pk.y = (unsigned)p[2] | ((unsigned)p[3] << 16);
            *(uint2*)(smem + (size_t)tl * 72 + dk0) = pk;
        }
    }
    __syncthreads();
    {
#pragma unroll
        for (int it = 0; it < 2; ++it) {
            int tl = it * 32 + (tid >> 3), part = tid & 7;
            uint4 v = *(const uint4*)(smem + (size_t)tl * 72 + part * 8);
            size_t base = ((size_t)((l * 2 + kvv) * NTOK + r0 + tl)) * 512 + h * 64 + part * 8;
            *(uint4*)(KV + base) = v;
        }
    }
}

// ---------------------------------------------------------------------------
// ds gemm with fused gather: ATTV = encoded[:, i, mid_idx] @ ds_W + ds_b.
// A rows gathered as fp32 from encoded and converted inline.  K=256, N=512.
// grid (8, 32), block 256: wave = 1 ntile x 2 mtiles (32 rows).
// ---------------------------------------------------------------------------
__global__ __launch_bounds__(256) void gemm_ds(
    const float* __restrict__ enc, const int* __restrict__ mid,
    const int* __restrict__ ip, const unsigned short* __restrict__ WF,
    const float* __restrict__ bias, float* __restrict__ outf) {
    int tid = threadIdx.x, wv = tid >> 6, lane = tid & 63;
    int id = lane & 15, quad = lane >> 4;
    int ntile = blockIdx.x * 4 + wv;
    int n0 = ntile * 16, m0 = blockIdx.y * 32;
    int iv = ip[0];
    int r0 = m0 + id, r1 = m0 + 16 + id;
    const float* a0p = enc + (((size_t)((r0 >> 7) * 8 + iv)) * 256 + mid[r0 & 127]) * 256 + quad * 8;
    const float* a1p = enc + (((size_t)((r1 >> 7) * 8 + iv)) * 256 + mid[r1 & 127]) * 256 + quad * 8;
    f32x4 acc[2];
    acc[0] = (f32x4){0.f, 0.f, 0.f, 0.f};
    acc[1] = (f32x4){0.f, 0.f, 0.f, 0.f};
#pragma unroll
    for (int kc = 0; kc < 8; ++kc) {
        short8 bw = *(const short8*)(WF + (size_t)((kc * 32 + ntile) * 64 + lane) * 8);
        float4 u0 = *(const float4*)(a0p + kc * 32);
        float4 u1 = *(const float4*)(a0p + kc * 32 + 4);
        float4 w0 = *(const float4*)(a1p + kc * 32);
        float4 w1 = *(const float4*)(a1p + kc * 32 + 4);
        short8 a0, a1;
        a0[0] = (short)f2bf(u0.x); a0[1] = (short)f2bf(u0.y); a0[2] = (short)f2bf(u0.z); a0[3] = (short)f2bf(u0.w);
        a0[4] = (short)f2bf(u1.x); a0[5] = (short)f2bf(u1.y); a0[6] = (short)f2bf(u1.z); a0[7] = (short)f2bf(u1.w);
        a1[0] = (short)f2bf(w0.x); a1[1] = (short)f2bf(w0.y); a1[2] = (short)f2bf(w0.z); a1[3] = (short)f2bf(w0.w);
        a1[4] = (short)f2bf(w1.x); a1[5] = (short)f2bf(w1.y); a1[6] = (short)f2bf(w1.z); a1[7] = (short)f2bf(w1.w);
        acc[0] = __builtin_amdgcn_mfma_f32_16x16x32_bf16(a0, bw, acc[0], 0, 0, 0);
        acc[1] = __builtin_amdgcn_mfma_f32_16x16x32_bf16(a1, bw, acc[1], 0, 0, 0);
    }
    float bv = bias[n0 + id];
#pragma unroll
    for (int mt = 0; mt < 2; ++mt) {
#pragma unroll
        for (int r = 0; r < 4; ++r) {
            int row = m0 + mt * 16 + quad * 4 + r;
            outf[(size_t)row * 512 + n0 + id] = acc[mt][r] + bv;
        }
    }
}

// ---------------------------------------------------------------------------
// bf16 MFMA gemm with 1-deep prefetch:
// out = [relu](A[1024xK]bf16 @ W[KxN]bf16 + bias [+ res_f32])
// grid (N/64, 32), block 256: wave = 1 ntile x 2 mtiles (32 rows).
// ---------------------------------------------------------------------------
__global__ __launch_bounds__(256) void gemm_bf16(
    const unsigned short* __restrict__ A, const unsigned short* __restrict__ WF,
    const float* __restrict__ bias, const float* __restrict__ res,
    float* __restrict__ outf, unsigned short* __restrict__ outb,
    int K, int N, int relu) {
    int tid = threadIdx.x, wv = tid >> 6, lane = tid & 63;
    int id = lane & 15, quad = lane >> 4;
    int ntile = blockIdx.x * 4 + wv;
    int n0 = ntile * 16, m0 = blockIdx.y * 32;
    int NTl = N >> 4, KC = K >> 5;
    f32x4 acc[2];
    acc[0] = (f32x4){0.f, 0.f, 0.f, 0.f};
    acc[1] = (f32x4){0.f, 0.f, 0.f, 0.f};
    short8 bw = *(const short8*)(WF + (size_t)(ntile * 64 + lane) * 8);
    short8 a0 = *(const short8*)(A + (size_t)(m0 + id) * K + quad * 8);
    short8 a1 = *(const short8*)(A + (size_t)(m0 + 16 + id) * K + quad * 8);
    for (int kc = 0; kc < KC; ++kc) {
        short8 bwn, a0n, a1n;
        if (kc + 1 < KC) {
            bwn = *(const short8*)(WF + (size_t)(((kc + 1) * NTl + ntile) * 64 + lane) * 8);
            a0n = *(const short8*)(A + (size_t)(m0 + id) * K + (kc + 1) * 32 + quad * 8);
            a1n = *(const short8*)(A + (size_t)(m0 + 16 + id) * K + (kc + 1) * 32 + quad * 8);
        }
        acc[0] = __builtin_amdgcn_mfma_f32_16x16x32_bf16(a0, bw, acc[0], 0, 0, 0);
        acc[1] = __builtin_amdgcn_mfma_f32_16x16x32_bf16(a1, bw, acc[1], 0, 0, 0);
        bw = bwn; a0 = a0n; a1 = a1n;
    }
    float bv = bias[n0 + id];
#pragma unroll
    for (int mt = 0; mt < 2; ++mt) {
#pragma unroll
        for (int r = 0; r < 4; ++r) {
            int row = m0 + mt * 16 + quad * 4 + r;
            int n = n0 + id;
            float v = acc[mt][r] + bv;
            if (res) v += res[(size_t)row * N + n];
            if (relu) v = fmaxf(v, 0.f);
            if (outf) outf[(size_t)row * N + n] = v;
            if (outb) outb[(size_t)row * N + n] = f2bf(v);
        }
    }
}

// ---------------------------------------------------------------------------
// Attention (2 neighbors, softmax over n, sum over s) + residual + LN1.
// One wave per (b,m) row; lane = (h = lane>>3, d8 = lane&7), each lane owns
// 8 contiguous dk -> KV row reads are coalesced uint4 (1 KB per row).
// grid 256 x 256 thr.  fp32 out + bf16 out.
// ---------------------------------------------------------------------------
__global__ __launch_bounds__(256) void attn_ln(
    const float* __restrict__ attv, const unsigned short* __restrict__ keys,
    const unsigned short* __restrict__ vals, const int* __restrict__ left,
    const int* __restrict__ right, const int* __restrict__ ip,
    const float* __restrict__ g, const float* __restrict__ bb,
    float* __restrict__ xout, unsigned short* __restrict__ xoutb) {
    int tid = threadIdx.x, wv = tid >> 6, lane = tid & 63;
    int gid = blockIdx.x * 4 + wv;  // 0..1023 = b*128+m
    int b = gid >> 7, m = gid & 127;
    int iv = ip[0];
    int lt = left[m], rt = right[m];
    float av8[8], att8[8];
    {
        const float* avp = attv + (size_t)gid * 512 + lane * 8;
        float4 u0 = *(const float4*)(avp);
        float4 u1 = *(const float4*)(avp + 4);
        av8[0] = u0.x; av8[1] = u0.y; av8[2] = u0.z; av8[3] = u0.w;
        av8[4] = u1.x; av8[5] = u1.y; av8[6] = u1.z; av8[7] = u1.w;
    }
#pragma unroll
    for (int j = 0; j < 8; ++j) att8[j] = 0.f;
    for (int s = 0; s < 8; ++s) {
        int t1 = (s < iv) ? m : rt;
        size_t row0 = ((size_t)((b * 8 + s) * 256 + lt)) * 512 + lane * 8;
        size_t row1 = ((size_t)((b * 8 + s) * 256 + t1)) * 512 + lane * 8;
        uint4 k0u = *(const uint4*)(keys + row0);
        uint4 k1u = *(const uint4*)(keys + row1);
        uint4 v0u = *(const uint4*)(vals + row0);
        uint4 v1u = *(const uint4*)(vals + row1);
        const unsigned short* k0 = (const unsigned short*)&k0u;
        const unsigned short* k1 = (const unsigned short*)&k1u;
        const unsigned short* v0 = (const unsigned short*)&v0u;
        const unsigned short* v1 = (const unsigned short*)&v1u;
        float p0 = 0.f, p1 = 0.f;
#pragma unroll
        for (int j = 0; j < 8; ++j) {
            p0 += av8[j] * bf2f(k0[j]);
            p1 += av8[j] * bf2f(k1[j]);
        }
#pragma unroll
        for (int o = 1; o < 8; o <<= 1) {
            p0 += __shfl_xor(p0, o, 64);
            p1 += __shfl_xor(p1, o, 64);
        }
        p0 *= 0.125f; p1 *= 0.125f;
        float mx = fmaxf(p0, p1);
        float e0 = __expf(p0 - mx), e1 = __expf(p1 - mx);
        float inv = 1.f / (e0 + e1);
        float w0 = e0 * inv, w1 = e1 * inv;
#pragma unroll
        for (int j = 0; j < 8; ++j)
            att8[j] += w0 * bf2f(v0[j]) + w1 * bf2f(v1[j]);
    }
    float x8[8], sum = 0.f;
#pragma unroll
    for (int j = 0; j < 8; ++j) { x8[j] = av8[j] + att8[j]; sum += x8[j]; }
    float mu = wred(sum) * (1.f / 512.f);
    float s2 = 0.f;
#pragma unroll
    for (int j = 0; j < 8; ++j) { float d = x8[j] - mu; s2 += d * d; }
    float rs = rsqrtf(wred(s2) * (1.f / 512.f) + 1e-5f);
    {
        const float* gp = g + lane * 8;
        const float* bp = bb + lane * 8;
        float* of = xout + (size_t)gid * 512 + lane * 8;
        unsigned short* ob = xoutb + (size_t)gid * 512 + lane * 8;
        __align__(16) float vout[8];
        __align__(16) unsigned short pb[8];
#pragma unroll
        for (int j = 0; j < 8; ++j) {
            float v = (x8[j] - mu) * rs * gp[j] + bp[j];
            vout[j] = v; pb[j] = f2bf(v);
        }
        *(float4*)(of) = *(float4*)vout;
        *(float4*)(of + 4) = *(float4*)(vout + 4);
        *(uint4*)(ob) = *(uint4*)pb;
    }
}

// ---------------------------------------------------------------------------
// LayerNorm over 512, one wave per row, lane owns 8 contiguous cols.
// ---------------------------------------------------------------------------
__global__ __launch_bounds__(256) void ln_k(const float* __restrict__ in,
                                            const float* __restrict__ g,
                                            const float* __restrict__ bb,
                                            float* __restrict__ out,
                                            unsigned short* __restrict__ outb) {
    int tid = threadIdx.x, wv = tid >> 6, lane = tid & 63;
    int gid = blockIdx.x * 4 + wv;
    float x8[8], sum = 0.f;
    {
        const float* ip = in + (size_t)gid * 512 + lane * 8;
        float4 u0 = *(const float4*)(ip);
        float4 u1 = *(const float4*)(ip + 4);
        x8[0] = u0.x; x8[1] = u0.y; x8[2] = u0.z; x8[3] = u0.w;
        x8[4] = u1.x; x8[5] = u1.y; x8[6] = u1.z; x8[7] = u1.w;
    }
#pragma unroll
    for (int j = 0; j < 8; ++j) sum += x8[j];
    float mu = wred(sum) * (1.f / 512.f);
    float s2 = 0.f;
#pragma unroll
    for (int j = 0; j < 8; ++j) { float d = x8[j] - mu; s2 += d * d; }
    float rs = rsqrtf(wred(s2) * (1.f / 512.f) + 1e-5f);
    {
        const float* gp = g + lane * 8;
        const float* bp = bb + lane * 8;
        float* of = out + (size_t)gid * 512 + lane * 8;
        unsigned short* ob = outb + (size_t)gid * 512 + lane * 8;
        __align__(16) float vout[8];
        __align__(16) unsigned short pb[8];
#pragma unroll
        for (int j = 0; j < 8; ++j) {
            float v = (x8[j] - mu) * rs * gp[j] + bp[j];
            vout[j] = v; pb[j] = f2bf(v);
        }
        *(float4*)(of) = *(float4*)vout;
        *(float4*)(of + 4) = *(float4*)(vout + 4);
        *(uint4*)(ob) = *(uint4*)pb;
    }
}

// ---------------------------------------------------------------------------
extern "C" void kernel_launch(void* const* d_in, const int* in_sizes, int n_in,
                              void* d_out, int out_size, void* d_ws, size_t ws_size,
                              hipStream_t stream) {
    const float* encoded = (const float*)d_in[0];
    const float* true_u  = (const float*)d_in[1];
    const int* mid_idx   = (const int*)d_in[2];
    const int* left_idx  = (const int*)d_in[3];
    const int* right_idx = (const int*)d_in[4];
    const int* ip        = (const int*)d_in[5];
    const float* ds_W = (const float*)d_in[6];
    const float* ds_b = (const float*)d_in[7];
    const float* kW1 = (const float*)d_in[8];
    const float* kb1 = (const float*)d_in[9];
    const float* kW2 = (const float*)d_in[10];
    const float* kb2 = (const float*)d_in[11];
    const float* kW3 = (const float*)d_in[12];
    const float* kb3 = (const float*)d_in[13];
    const float* vW1 = (const float*)d_in[14];
    const float* vb1 = (const float*)d_in[15];
    const float* vW2 = (const float*)d_in[16];
    const float* vb2 = (const float*)d_in[17];
    const float* vW3 = (const float*)d_in[18];
    const float* vb3 = (const float*)d_in[19];
    const float* ln1_g = (const float*)d_in[20];
    const float* ln1_b = (const float*)d_in[21];
    const float* ln2_g = (const float*)d_in[22];
    const float* ln2_b = (const float*)d_in[23];
    const float* ffW1 = (const float*)d_in[24];
    const float* ffb1 = (const float*)d_in[25];
    const float* ffW2 = (const float*)d_in[26];
    const float* ffb2 = (const float*)d_in[27];
    const float* deW1 = (const float*)d_in[28];
    const float* deb1 = (const float*)d_in[29];
    const float* deW2 = (const float*)d_in[30];
    const float* deb2 = (const float*)d_in[31];
    const float* deW3 = (const float*)d_in[32];
    const float* deb3 = (const float*)d_in[33];

    char* ws = (char*)d_ws;
    unsigned short* XF   = (unsigned short*)(ws + 0);          //  8,388,608
    unsigned short* WP   = (unsigned short*)(ws + 8388608);    //  9,437,184
    float* W1L           = (float*)(ws + 17825792);            //     32,768
    unsigned short* KV   = (unsigned short*)(ws + 17858560);   // 67,108,864
    unsigned short* WG   = (unsigned short*)(ws + 84967424);   //  3,014,656
    float* ATTV          = (float*)(ws + 87982080);            //  2,097,152
    float* XBUF          = (float*)(ws + 90079232);            //  2,097,152
    float* YBUF          = (float*)(ws + 92176384);            //  2,097,152
    unsigned short* ATTVB = (unsigned short*)(ws + 94797824);  //  1,048,576
    unsigned short* XBUFB = (unsigned short*)(ws + 95846400);  //  1,048,576
    unsigned short* FBUFB = (unsigned short*)(ws + 96894976);  //  1,048,576 (end 97,943,552)
    unsigned short* DE1B = XBUFB;   // reuse (free after layers)
    unsigned short* DE2B = FBUFB;

    // WG image offsets (halves)
    unsigned short* WGds  = WG + 0;
    unsigned short* WGff1_0 = WG + 131072;
    unsigned short* WGff1_1 = WG + 393216;
    unsigned short* WGff2_0 = WG + 655360;
    unsigned short* WGff2_1 = WG + 917504;
    unsigned short* WGde1 = WG + 1179648;
    unsigned short* WGde2 = WG + 1310720;
    unsigned short* WGde3 = WG + 1376256;

    prep_all<<<1648, 256, 0, stream>>>(encoded, kW1, kW2, kW3, vW1, vW2, vW3,
                                       ds_W, ffW1, ffW2, deW1, deW2, deW3,
                                       XF, WP, W1L, WG);
    heads_mlp<<<8192, 256, 0, stream>>>(true_u, XF, WP, W1L, kb1, kb2, kb3,
                                        vb1, vb2, vb3, KV);
    gemm_ds<<<dim3(8, 32), 256, 0, stream>>>(encoded, mid_idx, ip, WGds, ds_b, ATTV);
    for (int l = 0; l < 2; ++l) {
        const unsigned short* keys = KV + (size_t)(l * 2) * NTOK * NHD;
        const unsigned short* vals = KV + (size_t)(l * 2 + 1) * NTOK * NHD;
        attn_ln<<<256, 256, 0, stream>>>(ATTV, keys, vals, left_idx, right_idx, ip,
                                         ln1_g + l * 512, ln1_b + l * 512, XBUF, XBUFB);
        gemm_bf16<<<dim3(8, 32), 256, 0, stream>>>(XBUFB, (l ? WGff1_1 : WGff1_0),
                                                   ffb1 + l * 512, nullptr,
                                                   nullptr, FBUFB, 512, 512, 1);
        gemm_bf16<<<dim3(8, 32), 256, 0, stream>>>(FBUFB, (l ? WGff2_1 : WGff2_0),
                                                   ffb2 + l * 512, XBUF,
                                                   YBUF, nullptr, 512, 512, 0);
        ln_k<<<256, 256, 0, stream>>>(YBUF, ln2_g + l * 512, ln2_b + l * 512, ATTV, ATTVB);
    }
    gemm_bf16<<<dim3(4, 32), 256, 0, stream>>>(ATTVB, WGde1, deb1, nullptr,
                                               nullptr, DE1B, 512, 256, 1);
    gemm_bf16<<<dim3(4, 32), 256, 0, stream>>>(DE1B, WGde2, deb2, nullptr,
                                               nullptr, DE2B, 256, 256, 1);
    gemm_bf16<<<dim3(8, 32), 256, 0, stream>>>(DE2B, WGde3, deb3, nullptr,
                                               (float*)d_out, nullptr, 256, 512, 0);
}